// Round 6
// baseline (961.420 us; speedup 1.0000x reference)
//
#include <hip/hip_runtime.h>
#include <hip/hip_bf16.h>
#include <cstdint>
#include <cstddef>

#define BB    2
#define TSEQ  512
#define EDIM  768
#define NHEAD 12
#define HDIM  64
#define VDIM  256
#define PDIM  4
#define NROW  (BB*TSEQ)        // 1024
#define NROW2 (BB*TSEQ*PDIM)   // 4096

typedef __attribute__((ext_vector_type(8))) short short8;
typedef __attribute__((ext_vector_type(4))) float floatx4;

__device__ __forceinline__ float gelu_f(float v){
    return 0.5f * v * (1.0f + erff(v * 0.70710678118654752f));
}
__device__ __forceinline__ float b2f(short s){
    unsigned u = ((unsigned)(unsigned short)s) << 16;
    float f; __builtin_memcpy(&f, &u, 4); return f;
}
__device__ __forceinline__ short f2bs(float v){
    __hip_bfloat16 h = __float2bfloat16(v);
    short s; __builtin_memcpy(&s, &h, 2); return s;
}
__device__ __forceinline__ void gload16(const void* g, void* l){
    __builtin_amdgcn_global_load_lds((const __attribute__((address_space(1))) void*)g,
                                     (__attribute__((address_space(3))) void*)l, 16, 0, 0);
}

// ---------------------------------------------------------------------------
// All weight conversions in one dispatch. fp32 [K,N] -> bf16 [N,K], with
// optional per-k LN-gain fold: out[n,k] = in[k,n] * g[k].
// ---------------------------------------------------------------------------
struct WD2 { const float* in; const float* g; __hip_bfloat16* out; int K; int N; int nt; };
struct WDs { WD2 d[17]; };

__global__ __launch_bounds__(256) void wconv_all(WDs a)
{
    int id = blockIdx.x;
    int i = 0;
    while(i < 16 && id >= a.d[i].nt){ id -= a.d[i].nt; i++; }
    WD2 w = a.d[i];
    const int tx = w.N / 32;
    const int n0 = (id % tx) * 32, k0 = (id / tx) * 32;
    __shared__ float t[32][33];
    const int c = threadIdx.x & 31, r0 = threadIdx.x >> 5;
    #pragma unroll
    for(int r = r0; r < 32; r += 8)
        t[r][c] = w.in[(size_t)(k0 + r) * w.N + n0 + c];
    const float gv = w.g ? w.g[k0 + c] : 1.0f;
    __syncthreads();
    #pragma unroll
    for(int r = r0; r < 32; r += 8)
        w.out[(size_t)(n0 + r) * w.K + k0 + c] = __float2bfloat16(t[c][r] * gv);
}

// ---------------------------------------------------------------------------
// LN-beta bias fold: ob[n] = (extb?extb[n]:0) + sum_k lnb[k] * Worig[k*N + n]
// (uses ORIGINAL fp32 weights so the gamma-fold in wconv doesn't corrupt it).
// ---------------------------------------------------------------------------
struct LB { const float* extb; const float* lnb; const float* w; float* ob; int N; int K; };
struct LBs { LB d[11]; };

__global__ __launch_bounds__(256) void lnbias(LBs a)
{
    int id = blockIdx.x;
    int i = 0;
    while(i < 10 && id >= a.d[i].N/256){ id -= a.d[i].N/256; i++; }
    LB w = a.d[i];
    const int n = id*256 + threadIdx.x;
    float acc = w.extb ? w.extb[n] : 0.f;
    for(int k = 0; k < w.K; k += 4){
        acc += w.lnb[k+0] * w.w[(size_t)(k+0)*w.N + n];
        acc += w.lnb[k+1] * w.w[(size_t)(k+1)*w.N + n];
        acc += w.lnb[k+2] * w.w[(size_t)(k+2)*w.N + n];
        acc += w.lnb[k+3] * w.w[(size_t)(k+3)*w.N + n];
    }
    w.ob[n] = acc;
}

// ---------------------------------------------------------------------------
// Fused LayerNorm + MFMA GEMM.  A fp32 [M,K] (optionally + A2), LN applied
// on the fly (gamma pre-folded into Bt, beta pre-folded into biasv).
// MT = 64 or 128 row tile; N tile = 128; BK = 32.
// EPI: 1 = bias+gelu bf16 store; 2 = phase-1 qkv RoPE scatter (MT=64);
//      3 = sa qkv RoPE (p=row&3) store (MT=128); 5 = bias fp32 store.
// ---------------------------------------------------------------------------
template<int MT, int EPI, int ADD2>
__global__ __launch_bounds__(256) void gemmln(
    const float* __restrict__ A, const float* __restrict__ A2,
    const short* __restrict__ Bt, const float* __restrict__ biasv,
    void* __restrict__ Cout,
    __hip_bfloat16* __restrict__ qrb, __hip_bfloat16* __restrict__ krb,
    __hip_bfloat16* __restrict__ vvb,
    const float* __restrict__ rc, const float* __restrict__ rs,
    int M, int N, int K)
{
    constexpr int MI = (MT == 64) ? 2 : 4;
    alignas(16) __shared__ short As[MT*32];
    alignas(16) __shared__ short Bs[128*32];
    __shared__ float smean[MT], srstd[MT];

    const int tid  = threadIdx.x;
    const int lane = tid & 63;
    const int wave = tid >> 6;
    const int bm = blockIdx.y * MT, bn = blockIdx.x * 128;
    const int wm = (wave >> 1) * (MT/2), wn = (wave & 1) * 64;
    const int quad = lane >> 4, l16 = lane & 15;

    // ---- per-row LN stats (fp32) ----
    {
        int sr, seg, off;
        if(MT == 64){ sr = tid >> 2; seg = K/4; off = (tid & 3) * seg; }
        else        { sr = tid >> 1; seg = K/2; off = (tid & 1) * seg; }
        const float* xr  = A + (size_t)(bm + sr) * K + off;
        const float* x2r = ADD2 ? A2 + (size_t)(bm + sr) * K + off : nullptr;
        float s = 0.f, q = 0.f;
        for(int j = 0; j < seg; j += 4){
            float4 v = *(const float4*)(xr + j);
            if(ADD2){ float4 w2 = *(const float4*)(x2r + j);
                      v.x += w2.x; v.y += w2.y; v.z += w2.z; v.w += w2.w; }
            s += v.x + v.y + v.z + v.w;
            q += v.x*v.x + v.y*v.y + v.z*v.z + v.w*v.w;
        }
        s += __shfl_xor(s, 1, 64); q += __shfl_xor(q, 1, 64);
        if(MT == 64){ s += __shfl_xor(s, 2, 64); q += __shfl_xor(q, 2, 64); }
        const int qt = (MT == 64) ? (tid & 3) : (tid & 1);
        if(qt == 0){
            float m = s / K;
            smean[sr] = m;
            srstd[sr] = rsqrtf(fmaxf(q / K - m*m, 0.f) + 1e-5f);
        }
    }
    __syncthreads();

    floatx4 acc[MI][4];
    #pragma unroll
    for(int i = 0; i < MI; i++)
        #pragma unroll
        for(int j = 0; j < 4; j++)
            acc[i][j] = floatx4{0.f, 0.f, 0.f, 0.f};

    const int r  = tid >> 2;
    const int c8 = (tid & 3) * 8;
    const int ldsoff = (tid & 192) * 16;
    const float m0 = smean[r], rs0 = srstd[r];
    float m1 = 0.f, rs1 = 0.f;
    if(MT == 128){ m1 = smean[r + 64]; rs1 = srstd[r + 64]; }

    for(int k0 = 0; k0 < K; k0 += 32){
        gload16(Bt + (size_t)(bn + r     ) * K + k0 + c8, (char*)Bs + ldsoff);
        gload16(Bt + (size_t)(bn + r + 64) * K + k0 + c8, (char*)Bs + 4096 + ldsoff);
        {
            const float* ap = A + (size_t)(bm + r) * K + k0 + c8;
            float4 v0 = *(const float4*)(ap), v1 = *(const float4*)(ap + 4);
            if(ADD2){
                const float* a2p = A2 + (size_t)(bm + r) * K + k0 + c8;
                float4 w0 = *(const float4*)(a2p), w1 = *(const float4*)(a2p + 4);
                v0.x += w0.x; v0.y += w0.y; v0.z += w0.z; v0.w += w0.w;
                v1.x += w1.x; v1.y += w1.y; v1.z += w1.z; v1.w += w1.w;
            }
            short8 pk;
            pk[0] = f2bs((v0.x - m0)*rs0); pk[1] = f2bs((v0.y - m0)*rs0);
            pk[2] = f2bs((v0.z - m0)*rs0); pk[3] = f2bs((v0.w - m0)*rs0);
            pk[4] = f2bs((v1.x - m0)*rs0); pk[5] = f2bs((v1.y - m0)*rs0);
            pk[6] = f2bs((v1.z - m0)*rs0); pk[7] = f2bs((v1.w - m0)*rs0);
            *(short8*)&As[r*32 + c8] = pk;
        }
        if(MT == 128){
            const float* ap = A + (size_t)(bm + r + 64) * K + k0 + c8;
            float4 v0 = *(const float4*)(ap), v1 = *(const float4*)(ap + 4);
            short8 pk;
            pk[0] = f2bs((v0.x - m1)*rs1); pk[1] = f2bs((v0.y - m1)*rs1);
            pk[2] = f2bs((v0.z - m1)*rs1); pk[3] = f2bs((v0.w - m1)*rs1);
            pk[4] = f2bs((v1.x - m1)*rs1); pk[5] = f2bs((v1.y - m1)*rs1);
            pk[6] = f2bs((v1.z - m1)*rs1); pk[7] = f2bs((v1.w - m1)*rs1);
            *(short8*)&As[(r + 64)*32 + c8] = pk;
        }
        __syncthreads();
        short8 af[MI], bfr[4];
        #pragma unroll
        for(int i = 0; i < MI; i++)
            af[i]  = *(const short8*)&As[(wm + i*16 + l16)*32 + quad*8];
        #pragma unroll
        for(int j = 0; j < 4; j++)
            bfr[j] = *(const short8*)&Bs[(wn + j*16 + l16)*32 + quad*8];
        #pragma unroll
        for(int i = 0; i < MI; i++)
            #pragma unroll
            for(int j = 0; j < 4; j++)
                acc[i][j] = __builtin_amdgcn_mfma_f32_16x16x32_bf16(af[i], bfr[j], acc[i][j], 0, 0, 0);
        __syncthreads();
    }

    float* Cf = (float*)Cout;
    __hip_bfloat16* Cb = (__hip_bfloat16*)Cout;

    if(EPI == 2 || EPI == 3){
        const int hb = bn + wn;            // 64-col group base
        const int region = hb / 768;       // 0=q, 1=k, 2=v
        const int h = (hb % 768) >> 6;
        float bj0 = biasv ? biasv[hb + l16]      : 0.f;
        float bj1 = biasv ? biasv[hb + 16 + l16] : 0.f;
        float bj2 = biasv ? biasv[hb + 32 + l16] : 0.f;
        float bj3 = biasv ? biasv[hb + 48 + l16] : 0.f;
        #pragma unroll
        for(int i = 0; i < MI; i++){
            #pragma unroll
            for(int rr = 0; rr < 4; rr++){
                int row = bm + wm + i*16 + quad*4 + rr;
                float a0 = acc[i][0][rr] + bj0, a1 = acc[i][1][rr] + bj1;
                float a2 = acc[i][2][rr] + bj2, a3 = acc[i][3][rr] + bj3;
                if(EPI == 2){
                    int t = row & (TSEQ-1), b = row >> 9;
                    size_t dbase = ((size_t)(b*NHEAD + h)*TSEQ + t)*HDIM;
                    if(region == 2){
                        vvb[dbase + l16]      = __float2bfloat16(a0);
                        vvb[dbase + 16 + l16] = __float2bfloat16(a1);
                        vvb[dbase + 32 + l16] = __float2bfloat16(a2);
                        vvb[dbase + 48 + l16] = __float2bfloat16(a3);
                    }else{
                        float c0 = rc[t*32 + l16],      s0 = rs[t*32 + l16];
                        float c1 = rc[t*32 + 16 + l16], s1 = rs[t*32 + 16 + l16];
                        __hip_bfloat16* dst = (region == 0) ? qrb : krb;
                        dst[dbase + l16]      = __float2bfloat16(a0*c0 - a2*s0);
                        dst[dbase + 16 + l16] = __float2bfloat16(a1*c1 - a3*s1);
                        dst[dbase + 32 + l16] = __float2bfloat16(a0*s0 + a2*c0);
                        dst[dbase + 48 + l16] = __float2bfloat16(a1*s1 + a3*c1);
                    }
                }else{ // EPI == 3
                    size_t rowb = (size_t)row * N + hb;
                    if(region == 2){
                        Cb[rowb + l16]      = __float2bfloat16(a0);
                        Cb[rowb + 16 + l16] = __float2bfloat16(a1);
                        Cb[rowb + 32 + l16] = __float2bfloat16(a2);
                        Cb[rowb + 48 + l16] = __float2bfloat16(a3);
                    }else{
                        int p = row & 3;
                        float c0 = rc[p*32 + l16],      s0 = rs[p*32 + l16];
                        float c1 = rc[p*32 + 16 + l16], s1 = rs[p*32 + 16 + l16];
                        Cb[rowb + l16]      = __float2bfloat16(a0*c0 - a2*s0);
                        Cb[rowb + 16 + l16] = __float2bfloat16(a1*c1 - a3*s1);
                        Cb[rowb + 32 + l16] = __float2bfloat16(a0*s0 + a2*c0);
                        Cb[rowb + 48 + l16] = __float2bfloat16(a1*s1 + a3*c1);
                    }
                }
            }
        }
        return;
    }

    #pragma unroll
    for(int i = 0; i < MI; i++){
        int row0 = bm + wm + i*16 + quad*4;
        #pragma unroll
        for(int j = 0; j < 4; j++){
            int col = bn + wn + j*16 + l16;
            float bv = biasv ? biasv[col] : 0.f;
            #pragma unroll
            for(int rr = 0; rr < 4; rr++){
                float v = acc[i][j][rr] + bv;
                if(EPI == 1){ v = gelu_f(v); Cb[(size_t)(row0 + rr) * N + col] = __float2bfloat16(v); }
                else        {                Cf[(size_t)(row0 + rr) * N + col] = v; }
            }
        }
    }
}

// ---------------------------------------------------------------------------
// 64x64-tile GEMM (bf16 A) for non-LN layers; optional resid fp32 store and
// fused p==0 slice copy to out (OUTC).
// ---------------------------------------------------------------------------
template<int OUTC>
__global__ __launch_bounds__(256) void gemm64t(
    const short* __restrict__ A, const short* __restrict__ Bt,
    const float* __restrict__ bias, const float* __restrict__ resid,
    float* __restrict__ Cf, float* __restrict__ outp, int M, int N, int K)
{
    alignas(16) __shared__ short As[64*32];
    alignas(16) __shared__ short Bs[64*32];
    const int tid  = threadIdx.x;
    const int lane = tid & 63;
    const int wave = tid >> 6;
    const int bm = blockIdx.y * 64, bn = blockIdx.x * 64;
    const int wm = (wave >> 1) * 32, wn = (wave & 1) * 32;
    const int quad = lane >> 4, l16 = lane & 15;

    floatx4 acc[2][2];
    #pragma unroll
    for(int i = 0; i < 2; i++)
        #pragma unroll
        for(int j = 0; j < 2; j++)
            acc[i][j] = floatx4{0.f, 0.f, 0.f, 0.f};

    const int r  = tid >> 2;
    const int c8 = (tid & 3) * 8;
    const int ldsoff = (tid & 192) * 16;

    for(int k0 = 0; k0 < K; k0 += 32){
        gload16(A  + (size_t)(bm + r) * K + k0 + c8, (char*)As + ldsoff);
        gload16(Bt + (size_t)(bn + r) * K + k0 + c8, (char*)Bs + ldsoff);
        __syncthreads();
        short8 af[2], bfr[2];
        #pragma unroll
        for(int i = 0; i < 2; i++){
            af[i]  = *(const short8*)&As[(wm + i*16 + l16)*32 + quad*8];
            bfr[i] = *(const short8*)&Bs[(wn + i*16 + l16)*32 + quad*8];
        }
        #pragma unroll
        for(int i = 0; i < 2; i++)
            #pragma unroll
            for(int j = 0; j < 2; j++)
                acc[i][j] = __builtin_amdgcn_mfma_f32_16x16x32_bf16(af[i], bfr[j], acc[i][j], 0, 0, 0);
        __syncthreads();
    }

    #pragma unroll
    for(int i = 0; i < 2; i++){
        int row0 = bm + wm + i*16 + quad*4;
        #pragma unroll
        for(int j = 0; j < 2; j++){
            int col = bn + wn + j*16 + l16;
            float bv = bias ? bias[col] : 0.f;
            #pragma unroll
            for(int rr = 0; rr < 4; rr++){
                int row = row0 + rr;
                float v = acc[i][j][rr] + bv + resid[(size_t)row * N + col];
                Cf[(size_t)row * N + col] = v;
                if(OUTC && (row & 3) == 0)
                    outp[(size_t)(row >> 2) * N + col] = v;
            }
        }
    }
}

// ---------------------------------------------------------------------------
__global__ __launch_bounds__(192) void embed_kernel(
    const int* __restrict__ tokens, const float* __restrict__ emb,
    float* __restrict__ x0, float* __restrict__ x)
{
    const int row = blockIdx.x;
    const int tok = tokens[row];
    const float4* src = (const float4*)(emb + (size_t)tok * EDIM);
    float4* d0 = (float4*)(x0 + (size_t)row * EDIM);
    float4* d1 = (float4*)(x  + (size_t)row * EDIM);
    for(int i = threadIdx.x; i < EDIM/4; i += blockDim.x){
        float4 v = src[i]; d0[i] = v; d1[i] = v;
    }
}

// ---------------------------------------------------------------------------
__global__ __launch_bounds__(256) void rope_kernel(float* __restrict__ rc, float* __restrict__ rs)
{
    int i = blockIdx.x * 256 + threadIdx.x;   // 512*32 = 16384
    int pos = i >> 5, d = i & 31;
    float inv = powf(10000.0f, -(float)(2*d) / 64.0f);
    float f = (float)pos * inv;
    rc[i] = cosf(f);
    rs[i] = sinf(f);
}

// ---------------------------------------------------------------------------
// Sliding-window attention. 4 waves/block = 4 consecutive queries.
// ---------------------------------------------------------------------------
template<int S>
__global__ __launch_bounds__(256) void patch_attn2(
    const __hip_bfloat16* __restrict__ qr, const __hip_bfloat16* __restrict__ kr,
    const __hip_bfloat16* __restrict__ vv, float* __restrict__ x)
{
    constexpr int W = S + 3;
    alignas(16) __shared__ short Ks[W*64];
    alignas(16) __shared__ short Vs[W*64];
    __shared__ float qlds[4*64];
    __shared__ float pb[4*128];

    const int t0 = blockIdx.x * 4;
    const int h = blockIdx.y, b = blockIdx.z;
    const int tid = threadIdx.x;
    const int wv = tid >> 6, lane = tid & 63;
    const size_t headbase = ((size_t)(b*NHEAD + h)) * TSEQ;

    const int c = tid & 7;
    for(int r = tid >> 3; r < W; r += 32){
        int g = t0 - S + 1 + r;
        int gc = g < 0 ? 0 : g;
        int sc = (c ^ (r & 7)) * 8;
        *(short8*)&Ks[r*64 + sc] = *(const short8*)((const short*)kr + (headbase + gc)*64 + c*8);
        *(short8*)&Vs[r*64 + sc] = *(const short8*)((const short*)vv + (headbase + gc)*64 + c*8);
    }
    qlds[wv*64 + lane] = __bfloat162float(qr[(headbase + t0 + wv)*64 + lane]);
    __syncthreads();

    const int t = t0 + wv;
    const int r0 = (S >= 64) ? (wv + lane) : ((lane < S) ? (wv + lane) : 0);
    const int r1 = wv + lane + 64;
    float a0 = 0.f, a1 = 0.f;
    #pragma unroll
    for(int ch = 0; ch < 8; ch++){
        float4 qa = *(const float4*)&qlds[wv*64 + ch*8];
        float4 qb = *(const float4*)&qlds[wv*64 + ch*8 + 4];
        short8 k0 = *(const short8*)&Ks[r0*64 + ((ch ^ (r0 & 7))*8)];
        a0 += qa.x*b2f(k0[0]) + qa.y*b2f(k0[1]) + qa.z*b2f(k0[2]) + qa.w*b2f(k0[3])
            + qb.x*b2f(k0[4]) + qb.y*b2f(k0[5]) + qb.z*b2f(k0[6]) + qb.w*b2f(k0[7]);
        if(S == 128){
            short8 k1 = *(const short8*)&Ks[r1*64 + ((ch ^ (r1 & 7))*8)];
            a1 += qa.x*b2f(k1[0]) + qa.y*b2f(k1[1]) + qa.z*b2f(k1[2]) + qa.w*b2f(k1[3])
                + qb.x*b2f(k1[4]) + qb.y*b2f(k1[5]) + qb.z*b2f(k1[6]) + qb.w*b2f(k1[7]);
        }
    }
    const int key0 = t - S + 1 + lane;
    const bool v0 = (lane < S) && (key0 >= 0);
    const bool v1 = (S == 128) && (key0 + 64 >= 0);
    float s0 = v0 ? a0 * 0.125f : -1e30f;
    float s1 = v1 ? a1 * 0.125f : -1e30f;
    float mx = fmaxf(s0, s1);
    #pragma unroll
    for(int off = 32; off > 0; off >>= 1) mx = fmaxf(mx, __shfl_xor(mx, off, 64));
    float p0 = v0 ? expf(s0 - mx) : 0.f;
    float p1 = v1 ? expf(s1 - mx) : 0.f;
    float sm = p0 + p1;
    #pragma unroll
    for(int off = 32; off > 0; off >>= 1) sm += __shfl_xor(sm, off, 64);
    const float inv = 1.f / sm;
    pb[wv*128 + lane] = p0 * inv;
    if(S == 128) pb[wv*128 + lane + 64] = p1 * inv;
    __syncthreads();

    const int d = lane;
    const int coff = d >> 3, dlo = d & 7;
    float o = 0.f;
    #pragma unroll 8
    for(int j = 0; j < S; j++){
        int r = wv + j;
        float p = pb[wv*128 + j];
        o += p * b2f(Vs[r*64 + ((coff ^ (r & 7))*8) + dlo]);
    }
    x[((size_t)(b*TSEQ) + t) * EDIM + h*HDIM + d] += o;
}

// ---------------------------------------------------------------------------
// P-axis attention: q/k already rotated by saqkv epilogue.
// ---------------------------------------------------------------------------
__global__ __launch_bounds__(256) void sa_attn(
    const __hip_bfloat16* __restrict__ qkv2, __hip_bfloat16* __restrict__ o)
{
    const int t = blockIdx.x, h = blockIdx.y, b = blockIdx.z;
    const int p = threadIdx.x >> 6, lane = threadIdx.x & 63;
    const int row0 = (b*TSEQ + t) * PDIM;
    const short* base = (const short*)qkv2 + (size_t)row0 * (3*EDIM);
    const int d = lane;
    float q = b2f(base[(size_t)p*(3*EDIM) + h*HDIM + d]);
    float sc[4];
    #pragma unroll
    for(int j = 0; j < 4; j++){
        float kj = b2f(base[(size_t)j*(3*EDIM) + EDIM + h*HDIM + d]);
        float v = q * kj;
        #pragma unroll
        for(int off = 32; off > 0; off >>= 1) v += __shfl_xor(v, off, 64);
        sc[j] = v * 0.125f;
    }
    float m = fmaxf(fmaxf(sc[0], sc[1]), fmaxf(sc[2], sc[3]));
    float e0 = expf(sc[0]-m), e1 = expf(sc[1]-m), e2 = expf(sc[2]-m), e3 = expf(sc[3]-m);
    float idn = 1.f / (e0 + e1 + e2 + e3);
    float ov = (e0 * b2f(base[0*(3*EDIM) + 2*EDIM + h*HDIM + d])
              + e1 * b2f(base[1*(3*EDIM) + 2*EDIM + h*HDIM + d])
              + e2 * b2f(base[2*(3*EDIM) + 2*EDIM + h*HDIM + d])
              + e3 * b2f(base[3*(3*EDIM) + 2*EDIM + h*HDIM + d])) * idn;
    o[(size_t)(row0 + p) * EDIM + h*HDIM + d] = __float2bfloat16(ov);
}

// ---------------------------------------------------------------------------
extern "C" void kernel_launch(void* const* d_in, const int* in_sizes, int n_in,
                              void* d_out, int out_size, void* d_ws, size_t ws_size,
                              hipStream_t stream)
{
    const int*   tokens    = (const int*)  d_in[0];
    const float* emb       = (const float*)d_in[1];
    const float* bl0g      = (const float*)d_in[2];
    const float* bl0b      = (const float*)d_in[3];
    const float* bl1g      = (const float*)d_in[4];
    const float* bl1b      = (const float*)d_in[5];
    const float* qkv_w     = (const float*)d_in[6];
    const float* ff_w1     = (const float*)d_in[7];
    const float* ff_b1     = (const float*)d_in[8];
    const float* ff_w2     = (const float*)d_in[9];
    const float* ff_b2     = (const float*)d_in[10];
    const float* fin_g     = (const float*)d_in[11];
    const float* fin_b     = (const float*)d_in[12];
    const float* head_w    = (const float*)d_in[13];
    const float* head_b    = (const float*)d_in[14];
    const float* sa_ln0_g  = (const float*)d_in[15];
    const float* sa_ln0_b  = (const float*)d_in[16];
    const float* sa_ln1_g  = (const float*)d_in[17];
    const float* sa_ln1_b  = (const float*)d_in[18];
    const float* sa_qkv_w  = (const float*)d_in[19];
    const float* sa_proj_w = (const float*)d_in[20];
    const float* sa_proj_b = (const float*)d_in[21];
    const float* sa_ff_w1  = (const float*)d_in[22];
    const float* sa_ff_b1  = (const float*)d_in[23];
    const float* sa_ff_w2  = (const float*)d_in[24];
    const float* sa_ff_b2  = (const float*)d_in[25];
    float* out = (float*)d_out;

    // ---- workspace carve-up (ws >= ~94 MB needed; harness provides 256 MiB) ----
    char* p = (char*)d_ws;
    auto alloc = [&](size_t bytes){ char* q = p; p += (bytes + 255) & ~(size_t)255; return q; };

    float* logits = (float*)alloc((size_t)NROW2*VDIM*4);        // 4 MB
    float* ropec  = (float*)alloc(512*32*4);
    float* ropes  = (float*)alloc(512*32*4);
    float* qkvb[4];  for(int i=0;i<4;i++) qkvb[i]  = (float*)alloc(2304*4);
    float* ff1b[4];  for(int i=0;i<4;i++) ff1b[i]  = (float*)alloc(3072*4);
    float* headb  = (float*)alloc(1024*4);
    float* saqkvb = (float*)alloc(2304*4);
    float* saff1b = (float*)alloc(1024*4);
    __hip_bfloat16* wqkvT[4]; for(int i=0;i<4;i++) wqkvT[i] = (__hip_bfloat16*)alloc((size_t)768*2304*2);
    __hip_bfloat16* wff1T[4]; for(int i=0;i<4;i++) wff1T[i] = (__hip_bfloat16*)alloc((size_t)768*3072*2);
    __hip_bfloat16* wff2T[4]; for(int i=0;i<4;i++) wff2T[i] = (__hip_bfloat16*)alloc((size_t)3072*768*2);
    __hip_bfloat16* wheadT   = (__hip_bfloat16*)alloc((size_t)768*1024*2);
    __hip_bfloat16* wsaqkvT  = (__hip_bfloat16*)alloc((size_t)256*2304*2);
    __hip_bfloat16* wsaprojT = (__hip_bfloat16*)alloc((size_t)768*256*2);
    __hip_bfloat16* wsaff1T  = (__hip_bfloat16*)alloc((size_t)256*1024*2);
    __hip_bfloat16* wsaff2T  = (__hip_bfloat16*)alloc((size_t)1024*256*2);
    char* U = p;
    // phase 1
    float* x0           = (float*)(U);
    float* x            = (float*)(U + 3145728);
    __hip_bfloat16* ff1 = (__hip_bfloat16*)(U + 6291456);        // 6,291,456
    __hip_bfloat16* qrb = (__hip_bfloat16*)(U + 12582912);
    __hip_bfloat16* krb = (__hip_bfloat16*)(U + 14155776);
    __hip_bfloat16* vvb = (__hip_bfloat16*)(U + 15728640);       // ends U+17,301,504
    // phase 2 (aliases phase 1 — dead by then)
    __hip_bfloat16* qkv2  = (__hip_bfloat16*)(U);                // 18,874,368
    __hip_bfloat16* sa_o  = (__hip_bfloat16*)(U + 18874368);     // 6,291,456
    __hip_bfloat16* sa_f1 = (__hip_bfloat16*)(U + 25165824);     // 8,388,608

    // ---- prologue: embed + rope + all 17 weight converts + beta folds ----
    embed_kernel<<<NROW, 192, 0, stream>>>(tokens, emb, x0, x);
    rope_kernel<<<64, 256, 0, stream>>>(ropec, ropes);
    {
        WDs wds; int tot = 0, n = 0;
        auto add = [&](const float* in, const float* g, __hip_bfloat16* o2, int K, int N){
            wds.d[n++] = WD2{in, g, o2, K, N, (N/32)*(K/32)};
            tot += (N/32)*(K/32);
        };
        for(int i=0;i<4;i++){
            add(qkv_w + (size_t)i*768*2304, bl0g + i*768, wqkvT[i], 768, 2304);
            add(ff_w1 + (size_t)i*768*3072, bl1g + i*768, wff1T[i], 768, 3072);
            add(ff_w2 + (size_t)i*3072*768, nullptr,      wff2T[i], 3072, 768);
        }
        add(head_w,    fin_g,    wheadT,   768, 1024);
        add(sa_qkv_w,  sa_ln0_g, wsaqkvT,  256, 2304);
        add(sa_proj_w, nullptr,  wsaprojT, 768, 256);
        add(sa_ff_w1,  sa_ln1_g, wsaff1T,  256, 1024);
        add(sa_ff_w2,  nullptr,  wsaff2T, 1024, 256);
        wconv_all<<<tot, 256, 0, stream>>>(wds);
    }
    {
        LBs lbs; int tot = 0, n = 0;
        auto add = [&](const float* extb, const float* lnb, const float* w, float* ob, int N, int K){
            lbs.d[n++] = LB{extb, lnb, w, ob, N, K};
            tot += N/256;
        };
        for(int i=0;i<4;i++){
            add(nullptr,          bl0b + i*768, qkv_w + (size_t)i*768*2304, qkvb[i], 2304, 768);
            add(ff_b1 + i*3072,   bl1b + i*768, ff_w1 + (size_t)i*768*3072, ff1b[i], 3072, 768);
        }
        add(head_b,   fin_b,    head_w,   headb,  1024, 768);
        add(nullptr,  sa_ln0_b, sa_qkv_w, saqkvb, 2304, 256);
        add(sa_ff_b1, sa_ln1_b, sa_ff_w1, saff1b, 1024, 256);
        lnbias<<<tot, 256, 0, stream>>>(lbs);
    }

    // ---- 4 main layers (LN fused into qkv / ff1 GEMMs) ----
    for(int i = 0; i < 4; i++){
        gemmln<64,2,0><<<dim3(18, 16), 256, 0, stream>>>(
            x, nullptr, (const short*)wqkvT[i], qkvb[i], nullptr,
            qrb, krb, vvb, ropec, ropes, NROW, 3*EDIM, EDIM);
        dim3 agrid(TSEQ/4, NHEAD, BB);
        if(i == 0)      patch_attn2<16><<<agrid, 256, 0, stream>>>(qrb, krb, vvb, x);
        else if(i == 1) patch_attn2<32><<<agrid, 256, 0, stream>>>(qrb, krb, vvb, x);
        else if(i == 2) patch_attn2<64><<<agrid, 256, 0, stream>>>(qrb, krb, vvb, x);
        else            patch_attn2<128><<<agrid, 256, 0, stream>>>(qrb, krb, vvb, x);
        gemmln<64,1,0><<<dim3(24, 16), 256, 0, stream>>>(
            x, nullptr, (const short*)wff1T[i], ff1b[i], ff1,
            nullptr, nullptr, nullptr, nullptr, nullptr, NROW, 4*EDIM, EDIM);
        gemm64t<0><<<dim3(12, 16), 256, 0, stream>>>(
            (const short*)ff1, (const short*)wff2T[i], ff_b2 + (size_t)i*EDIM, x, x, nullptr,
            NROW, EDIM, 4*EDIM);
    }

    // ---- head: fin_ln(x0+x) fused ----
    gemmln<64,5,1><<<dim3(8, 16), 256, 0, stream>>>(
        x, x0, (const short*)wheadT, headb, logits,
        nullptr, nullptr, nullptr, nullptr, nullptr, NROW, PDIM*VDIM, EDIM);

    // ---- sa block ----
    gemmln<128,3,0><<<dim3(18, 32), 256, 0, stream>>>(
        logits, nullptr, (const short*)wsaqkvT, saqkvb, qkv2,
        nullptr, nullptr, nullptr, ropec, ropes, NROW2, 3*EDIM, VDIM);
    sa_attn<<<dim3(TSEQ, NHEAD, BB), 256, 0, stream>>>(qkv2, sa_o);
    gemm64t<0><<<dim3(4, 64), 256, 0, stream>>>(
        (const short*)sa_o, (const short*)wsaprojT, sa_proj_b, logits, logits, nullptr,
        NROW2, VDIM, EDIM);
    gemmln<128,1,0><<<dim3(8, 32), 256, 0, stream>>>(
        logits, nullptr, (const short*)wsaff1T, saff1b, sa_f1,
        nullptr, nullptr, nullptr, nullptr, nullptr, NROW2, 4*VDIM, VDIM);
    gemm64t<1><<<dim3(4, 64), 256, 0, stream>>>(
        (const short*)sa_f1, (const short*)wsaff2T, sa_ff_b2, logits, logits, out,
        NROW2, VDIM, 4*VDIM);
}

// Round 7
// 704.092 us; speedup vs baseline: 1.3655x; 1.3655x over previous
//
#include <hip/hip_runtime.h>
#include <hip/hip_bf16.h>
#include <cstdint>
#include <cstddef>

#define BB    2
#define TSEQ  512
#define EDIM  768
#define NHEAD 12
#define HDIM  64
#define VDIM  256
#define PDIM  4
#define NROW  (BB*TSEQ)        // 1024
#define NROW2 (BB*TSEQ*PDIM)   // 4096

typedef __attribute__((ext_vector_type(8))) short short8;
typedef __attribute__((ext_vector_type(4))) float floatx4;

__device__ __forceinline__ float gelu_f(float v){
    return 0.5f * v * (1.0f + erff(v * 0.70710678118654752f));
}
__device__ __forceinline__ float b2f(short s){
    unsigned u = ((unsigned)(unsigned short)s) << 16;
    float f; __builtin_memcpy(&f, &u, 4); return f;
}
__device__ __forceinline__ short f2bs(float v){
    __hip_bfloat16 h = __float2bfloat16(v);
    short s; __builtin_memcpy(&s, &h, 2); return s;
}
__device__ __forceinline__ void gload16(const void* g, void* l){
    __builtin_amdgcn_global_load_lds((const __attribute__((address_space(1))) void*)g,
                                     (__attribute__((address_space(3))) void*)l, 16, 0, 0);
}

// ---------------------------------------------------------------------------
// All 17 weight conversions in one dispatch. fp32 [K,N] -> bf16 [N,K].
// 64x64 tiles: 128B coalesced bf16 writes (vs 64B with 32-tiles).
// ---------------------------------------------------------------------------
struct WD2 { const float* in; __hip_bfloat16* out; int K; int N; int nt; };
struct WDs { WD2 d[17]; };

__global__ __launch_bounds__(256) void wconv_all(WDs a)
{
    int id = blockIdx.x;
    int i = 0;
    while(i < 16 && id >= a.d[i].nt){ id -= a.d[i].nt; i++; }
    WD2 w = a.d[i];
    const int tx = w.N / 64;
    const int n0 = (id % tx) * 64, k0 = (id / tx) * 64;
    __shared__ float t[64][65];
    const int cg = (threadIdx.x & 15) * 4;
    const int rr = threadIdx.x >> 4;           // 0..15
    #pragma unroll
    for(int it = 0; it < 4; it++){
        int r = rr + it*16;
        float4 v = *(const float4*)(w.in + (size_t)(k0 + r) * w.N + n0 + cg);
        t[r][cg+0] = v.x; t[r][cg+1] = v.y; t[r][cg+2] = v.z; t[r][cg+3] = v.w;
    }
    __syncthreads();
    #pragma unroll
    for(int it = 0; it < 4; it++){
        int n = rr + it*16;
        short4 o;
        o.x = f2bs(t[cg+0][n]); o.y = f2bs(t[cg+1][n]);
        o.z = f2bs(t[cg+2][n]); o.w = f2bs(t[cg+3][n]);
        *(short4*)((short*)w.out + (size_t)(n0 + n) * w.K + k0 + cg) = o;
    }
}

// ---------------------------------------------------------------------------
// MFMA GEMM 128x128: C = op(A @ Bt^T (+bias)) (+resid)
// ROPESA=1: epilogue rotates q/k cols (RoPE at position p=row%4) before store.
// ---------------------------------------------------------------------------
template<int ACT, int RESID, int OUTBF16, int ROPESA>
__global__ __launch_bounds__(256) void gemm128(
    const short* __restrict__ A, const short* __restrict__ Bt,
    const float* __restrict__ bias, const float* __restrict__ resid,
    void* __restrict__ Cout, const float* __restrict__ rc, const float* __restrict__ rs,
    int M, int N, int K)
{
    alignas(16) __shared__ short As[128*32];
    alignas(16) __shared__ short Bs[128*32];
    const int tid  = threadIdx.x;
    const int lane = tid & 63;
    const int wave = tid >> 6;
    const int bm = blockIdx.y * 128, bn = blockIdx.x * 128;
    const int wm = (wave >> 1) * 64, wn = (wave & 1) * 64;
    const int quad = lane >> 4, l16 = lane & 15;

    floatx4 acc[4][4];
    #pragma unroll
    for(int i = 0; i < 4; i++)
        #pragma unroll
        for(int j = 0; j < 4; j++)
            acc[i][j] = floatx4{0.f, 0.f, 0.f, 0.f};

    const int r  = tid >> 2;
    const int c8 = (tid & 3) * 8;
    const int ldsoff = (tid & 192) * 16;

    for(int k0 = 0; k0 < K; k0 += 32){
        gload16(A  + (size_t)(bm + r     ) * K + k0 + c8, (char*)As + ldsoff);
        gload16(A  + (size_t)(bm + r + 64) * K + k0 + c8, (char*)As + 4096 + ldsoff);
        gload16(Bt + (size_t)(bn + r     ) * K + k0 + c8, (char*)Bs + ldsoff);
        gload16(Bt + (size_t)(bn + r + 64) * K + k0 + c8, (char*)Bs + 4096 + ldsoff);
        __syncthreads();
        short8 af[4], bfr[4];
        #pragma unroll
        for(int i = 0; i < 4; i++){
            af[i]  = *(const short8*)&As[(wm + i*16 + l16)*32 + quad*8];
            bfr[i] = *(const short8*)&Bs[(wn + i*16 + l16)*32 + quad*8];
        }
        #pragma unroll
        for(int i = 0; i < 4; i++)
            #pragma unroll
            for(int j = 0; j < 4; j++)
                acc[i][j] = __builtin_amdgcn_mfma_f32_16x16x32_bf16(af[i], bfr[j], acc[i][j], 0, 0, 0);
        __syncthreads();
    }

    float* Cf = (float*)Cout;
    __hip_bfloat16* Cb = (__hip_bfloat16*)Cout;

    if(ROPESA){
        const int hb = bn + wn;
        const int region = hb / 768;
        #pragma unroll
        for(int i = 0; i < 4; i++){
            #pragma unroll
            for(int rr = 0; rr < 4; rr++){
                int row = bm + wm + i*16 + quad*4 + rr;
                float a0 = acc[i][0][rr], a1 = acc[i][1][rr];
                float a2 = acc[i][2][rr], a3 = acc[i][3][rr];
                size_t rowb = (size_t)row * N + hb;
                if(region == 2){
                    Cb[rowb + l16]      = __float2bfloat16(a0);
                    Cb[rowb + 16 + l16] = __float2bfloat16(a1);
                    Cb[rowb + 32 + l16] = __float2bfloat16(a2);
                    Cb[rowb + 48 + l16] = __float2bfloat16(a3);
                }else{
                    int p = row & 3;
                    float c0 = rc[p*32 + l16],      s0 = rs[p*32 + l16];
                    float c1 = rc[p*32 + 16 + l16], s1 = rs[p*32 + 16 + l16];
                    Cb[rowb + l16]      = __float2bfloat16(a0*c0 - a2*s0);
                    Cb[rowb + 16 + l16] = __float2bfloat16(a1*c1 - a3*s1);
                    Cb[rowb + 32 + l16] = __float2bfloat16(a0*s0 + a2*c0);
                    Cb[rowb + 48 + l16] = __float2bfloat16(a1*s1 + a3*c1);
                }
            }
        }
        return;
    }

    #pragma unroll
    for(int i = 0; i < 4; i++){
        int row0 = bm + wm + i*16 + quad*4;
        #pragma unroll
        for(int j = 0; j < 4; j++){
            int col = bn + wn + j*16 + l16;
            float bv = bias ? bias[col] : 0.f;
            #pragma unroll
            for(int rr = 0; rr < 4; rr++){
                float v = acc[i][j][rr] + bv;
                if(ACT) v = gelu_f(v);
                if(RESID) v += resid[(size_t)(row0 + rr) * N + col];
                if(OUTBF16) Cb[(size_t)(row0 + rr) * N + col] = __float2bfloat16(v);
                else        Cf[(size_t)(row0 + rr) * N + col] = v;
            }
        }
    }
}

// ---------------------------------------------------------------------------
// MFMA GEMM 64x128. EPI: 1 = bias+gelu bf16 store,
// 2 = phase-1 qkv: RoPE-rotate q/k and write head-major qrb/krb/vvb.
// ---------------------------------------------------------------------------
template<int EPI>
__global__ __launch_bounds__(256) void gemm64x128(
    const short* __restrict__ A, const short* __restrict__ Bt,
    const float* __restrict__ bias, __hip_bfloat16* __restrict__ Cout,
    __hip_bfloat16* __restrict__ qrb, __hip_bfloat16* __restrict__ krb,
    __hip_bfloat16* __restrict__ vvb,
    const float* __restrict__ rc, const float* __restrict__ rs,
    int M, int N, int K)
{
    alignas(16) __shared__ short As[64*32];
    alignas(16) __shared__ short Bs[128*32];
    const int tid  = threadIdx.x;
    const int lane = tid & 63;
    const int wave = tid >> 6;
    const int bm = blockIdx.y * 64, bn = blockIdx.x * 128;
    const int wm = (wave >> 1) * 32, wn = (wave & 1) * 64;
    const int quad = lane >> 4, l16 = lane & 15;

    floatx4 acc[2][4];
    #pragma unroll
    for(int i = 0; i < 2; i++)
        #pragma unroll
        for(int j = 0; j < 4; j++)
            acc[i][j] = floatx4{0.f, 0.f, 0.f, 0.f};

    const int r  = tid >> 2;
    const int c8 = (tid & 3) * 8;
    const int ldsoff = (tid & 192) * 16;

    for(int k0 = 0; k0 < K; k0 += 32){
        gload16(A  + (size_t)(bm + r     ) * K + k0 + c8, (char*)As + ldsoff);
        gload16(Bt + (size_t)(bn + r     ) * K + k0 + c8, (char*)Bs + ldsoff);
        gload16(Bt + (size_t)(bn + r + 64) * K + k0 + c8, (char*)Bs + 4096 + ldsoff);
        __syncthreads();
        short8 af[2], bfr[4];
        #pragma unroll
        for(int i = 0; i < 2; i++)
            af[i]  = *(const short8*)&As[(wm + i*16 + l16)*32 + quad*8];
        #pragma unroll
        for(int j = 0; j < 4; j++)
            bfr[j] = *(const short8*)&Bs[(wn + j*16 + l16)*32 + quad*8];
        #pragma unroll
        for(int i = 0; i < 2; i++)
            #pragma unroll
            for(int j = 0; j < 4; j++)
                acc[i][j] = __builtin_amdgcn_mfma_f32_16x16x32_bf16(af[i], bfr[j], acc[i][j], 0, 0, 0);
        __syncthreads();
    }

    if(EPI == 2){
        const int hb = bn + wn;            // col base of this wave's 64 cols
        const int region = hb / 768;       // 0=q, 1=k, 2=v
        const int h = (hb % 768) >> 6;
        #pragma unroll
        for(int i = 0; i < 2; i++){
            #pragma unroll
            for(int rr = 0; rr < 4; rr++){
                int row = bm + wm + i*16 + quad*4 + rr;
                int t = row & (TSEQ-1), b = row >> 9;
                float a0 = acc[i][0][rr], a1 = acc[i][1][rr];
                float a2 = acc[i][2][rr], a3 = acc[i][3][rr];
                size_t dbase = ((size_t)(b*NHEAD + h)*TSEQ + t)*HDIM;
                if(region == 2){
                    vvb[dbase + l16]      = __float2bfloat16(a0);
                    vvb[dbase + 16 + l16] = __float2bfloat16(a1);
                    vvb[dbase + 32 + l16] = __float2bfloat16(a2);
                    vvb[dbase + 48 + l16] = __float2bfloat16(a3);
                }else{
                    float c0 = rc[t*32 + l16],      s0 = rs[t*32 + l16];
                    float c1 = rc[t*32 + 16 + l16], s1 = rs[t*32 + 16 + l16];
                    __hip_bfloat16* dst = (region == 0) ? qrb : krb;
                    dst[dbase + l16]      = __float2bfloat16(a0*c0 - a2*s0);
                    dst[dbase + 16 + l16] = __float2bfloat16(a1*c1 - a3*s1);
                    dst[dbase + 32 + l16] = __float2bfloat16(a0*s0 + a2*c0);
                    dst[dbase + 48 + l16] = __float2bfloat16(a1*s1 + a3*c1);
                }
            }
        }
        return;
    }

    #pragma unroll
    for(int i = 0; i < 2; i++){
        int row0 = bm + wm + i*16 + quad*4;
        #pragma unroll
        for(int j = 0; j < 4; j++){
            int col = bn + wn + j*16 + l16;
            float bv = bias ? bias[col] : 0.f;
            #pragma unroll
            for(int rr = 0; rr < 4; rr++){
                float v = acc[i][j][rr] + bv;
                if(EPI == 1) v = gelu_f(v);
                Cout[(size_t)(row0 + rr) * N + col] = __float2bfloat16(v);
            }
        }
    }
}

// ---------------------------------------------------------------------------
// 64x64-tile GEMM (bf16 A), fp32 out, optional resid add and fused p==0 copy.
// ---------------------------------------------------------------------------
template<int RESID, int OUTC>
__global__ __launch_bounds__(256) void gemm64t(
    const short* __restrict__ A, const short* __restrict__ Bt,
    const float* __restrict__ bias, const float* __restrict__ resid,
    float* __restrict__ Cf, float* __restrict__ outp, int M, int N, int K)
{
    alignas(16) __shared__ short As[64*32];
    alignas(16) __shared__ short Bs[64*32];
    const int tid  = threadIdx.x;
    const int lane = tid & 63;
    const int wave = tid >> 6;
    const int bm = blockIdx.y * 64, bn = blockIdx.x * 64;
    const int wm = (wave >> 1) * 32, wn = (wave & 1) * 32;
    const int quad = lane >> 4, l16 = lane & 15;

    floatx4 acc[2][2];
    #pragma unroll
    for(int i = 0; i < 2; i++)
        #pragma unroll
        for(int j = 0; j < 2; j++)
            acc[i][j] = floatx4{0.f, 0.f, 0.f, 0.f};

    const int r  = tid >> 2;
    const int c8 = (tid & 3) * 8;
    const int ldsoff = (tid & 192) * 16;

    for(int k0 = 0; k0 < K; k0 += 32){
        gload16(A  + (size_t)(bm + r) * K + k0 + c8, (char*)As + ldsoff);
        gload16(Bt + (size_t)(bn + r) * K + k0 + c8, (char*)Bs + ldsoff);
        __syncthreads();
        short8 af[2], bfr[2];
        #pragma unroll
        for(int i = 0; i < 2; i++){
            af[i]  = *(const short8*)&As[(wm + i*16 + l16)*32 + quad*8];
            bfr[i] = *(const short8*)&Bs[(wn + i*16 + l16)*32 + quad*8];
        }
        #pragma unroll
        for(int i = 0; i < 2; i++)
            #pragma unroll
            for(int j = 0; j < 2; j++)
                acc[i][j] = __builtin_amdgcn_mfma_f32_16x16x32_bf16(af[i], bfr[j], acc[i][j], 0, 0, 0);
        __syncthreads();
    }

    #pragma unroll
    for(int i = 0; i < 2; i++){
        int row0 = bm + wm + i*16 + quad*4;
        #pragma unroll
        for(int j = 0; j < 2; j++){
            int col = bn + wn + j*16 + l16;
            float bv = bias ? bias[col] : 0.f;
            #pragma unroll
            for(int rr = 0; rr < 4; rr++){
                int row = row0 + rr;
                float v = acc[i][j][rr] + bv;
                if(RESID) v += resid[(size_t)row * N + col];
                Cf[(size_t)row * N + col] = v;
                if(OUTC && (row & 3) == 0)
                    outp[(size_t)(row >> 2) * N + col] = v;
            }
        }
    }
}

// ---------------------------------------------------------------------------
// LayerNorm over last dim D. fp32 in (optionally +in2), bf16 out.
// ---------------------------------------------------------------------------
__global__ __launch_bounds__(256) void ln_kernel(
    const float* __restrict__ in, const float* __restrict__ in2,
    const float* __restrict__ g, const float* __restrict__ bta,
    __hip_bfloat16* __restrict__ out, int D)
{
    const int row = blockIdx.x;
    const float* xr  = in + (size_t)row * D;
    const float* x2r = in2 ? in2 + (size_t)row * D : nullptr;
    const int tid = threadIdx.x;
    const int nper = D / 256;
    float vals[3];
    float sum = 0.f, sq = 0.f;
    for(int i = 0; i < nper; i++){
        int d = tid + i*256;
        float v = xr[d];
        if(x2r) v += x2r[d];
        vals[i] = v; sum += v; sq += v*v;
    }
    #pragma unroll
    for(int off = 32; off > 0; off >>= 1){
        sum += __shfl_xor(sum, off, 64);
        sq  += __shfl_xor(sq,  off, 64);
    }
    __shared__ float ssum[4], ssq[4];
    __shared__ float smean, srstd;
    int wid = tid >> 6;
    if((tid & 63) == 0){ ssum[wid] = sum; ssq[wid] = sq; }
    __syncthreads();
    if(tid == 0){
        float S = 0.f, Q = 0.f;
        for(int w = 0; w < 4; w++){ S += ssum[w]; Q += ssq[w]; }
        float m = S / D;
        float var = Q / D - m*m;
        smean = m;
        srstd = rsqrtf(fmaxf(var, 0.f) + 1e-5f);
    }
    __syncthreads();
    float m = smean, rs2 = srstd;
    for(int i = 0; i < nper; i++){
        int d = tid + i*256;
        out[(size_t)row*D + d] = __float2bfloat16((vals[i] - m) * rs2 * g[d] + bta[d]);
    }
}

// ---------------------------------------------------------------------------
__global__ __launch_bounds__(192) void embed_kernel(
    const int* __restrict__ tokens, const float* __restrict__ emb,
    float* __restrict__ x0, float* __restrict__ x)
{
    const int row = blockIdx.x;
    const int tok = tokens[row];
    const float4* src = (const float4*)(emb + (size_t)tok * EDIM);
    float4* d0 = (float4*)(x0 + (size_t)row * EDIM);
    float4* d1 = (float4*)(x  + (size_t)row * EDIM);
    for(int i = threadIdx.x; i < EDIM/4; i += blockDim.x){
        float4 v = src[i]; d0[i] = v; d1[i] = v;
    }
}

// ---------------------------------------------------------------------------
__global__ __launch_bounds__(256) void rope_kernel(float* __restrict__ rc, float* __restrict__ rs)
{
    int i = blockIdx.x * 256 + threadIdx.x;   // 512*32 = 16384
    int pos = i >> 5, d = i & 31;
    float inv = powf(10000.0f, -(float)(2*d) / 64.0f);
    float f = (float)pos * inv;
    rc[i] = cosf(f);
    rs[i] = sinf(f);
}

// ---------------------------------------------------------------------------
// Sliding-window attention. 4 waves/block = 4 consecutive queries.
// ---------------------------------------------------------------------------
template<int S>
__global__ __launch_bounds__(256) void patch_attn2(
    const __hip_bfloat16* __restrict__ qr, const __hip_bfloat16* __restrict__ kr,
    const __hip_bfloat16* __restrict__ vv, float* __restrict__ x)
{
    constexpr int W = S + 3;
    alignas(16) __shared__ short Ks[W*64];
    alignas(16) __shared__ short Vs[W*64];
    __shared__ float qlds[4*64];
    __shared__ float pb[4*128];

    const int t0 = blockIdx.x * 4;
    const int h = blockIdx.y, b = blockIdx.z;
    const int tid = threadIdx.x;
    const int wv = tid >> 6, lane = tid & 63;
    const size_t headbase = ((size_t)(b*NHEAD + h)) * TSEQ;

    const int c = tid & 7;
    for(int r = tid >> 3; r < W; r += 32){
        int g = t0 - S + 1 + r;
        int gc = g < 0 ? 0 : g;
        int sc = (c ^ (r & 7)) * 8;
        *(short8*)&Ks[r*64 + sc] = *(const short8*)((const short*)kr + (headbase + gc)*64 + c*8);
        *(short8*)&Vs[r*64 + sc] = *(const short8*)((const short*)vv + (headbase + gc)*64 + c*8);
    }
    qlds[wv*64 + lane] = __bfloat162float(qr[(headbase + t0 + wv)*64 + lane]);
    __syncthreads();

    const int t = t0 + wv;
    const int r0 = (S >= 64) ? (wv + lane) : ((lane < S) ? (wv + lane) : 0);
    const int r1 = wv + lane + 64;
    float a0 = 0.f, a1 = 0.f;
    #pragma unroll
    for(int ch = 0; ch < 8; ch++){
        float4 qa = *(const float4*)&qlds[wv*64 + ch*8];
        float4 qb = *(const float4*)&qlds[wv*64 + ch*8 + 4];
        short8 k0 = *(const short8*)&Ks[r0*64 + ((ch ^ (r0 & 7))*8)];
        a0 += qa.x*b2f(k0[0]) + qa.y*b2f(k0[1]) + qa.z*b2f(k0[2]) + qa.w*b2f(k0[3])
            + qb.x*b2f(k0[4]) + qb.y*b2f(k0[5]) + qb.z*b2f(k0[6]) + qb.w*b2f(k0[7]);
        if(S == 128){
            short8 k1 = *(const short8*)&Ks[r1*64 + ((ch ^ (r1 & 7))*8)];
            a1 += qa.x*b2f(k1[0]) + qa.y*b2f(k1[1]) + qa.z*b2f(k1[2]) + qa.w*b2f(k1[3])
                + qb.x*b2f(k1[4]) + qb.y*b2f(k1[5]) + qb.z*b2f(k1[6]) + qb.w*b2f(k1[7]);
        }
    }
    const int key0 = t - S + 1 + lane;
    const bool v0 = (lane < S) && (key0 >= 0);
    const bool v1 = (S == 128) && (key0 + 64 >= 0);
    float s0 = v0 ? a0 * 0.125f : -1e30f;
    float s1 = v1 ? a1 * 0.125f : -1e30f;
    float mx = fmaxf(s0, s1);
    #pragma unroll
    for(int off = 32; off > 0; off >>= 1) mx = fmaxf(mx, __shfl_xor(mx, off, 64));
    float p0 = v0 ? expf(s0 - mx) : 0.f;
    float p1 = v1 ? expf(s1 - mx) : 0.f;
    float sm = p0 + p1;
    #pragma unroll
    for(int off = 32; off > 0; off >>= 1) sm += __shfl_xor(sm, off, 64);
    const float inv = 1.f / sm;
    pb[wv*128 + lane] = p0 * inv;
    if(S == 128) pb[wv*128 + lane + 64] = p1 * inv;
    __syncthreads();

    const int d = lane;
    const int coff = d >> 3, dlo = d & 7;
    float o = 0.f;
    #pragma unroll 8
    for(int j = 0; j < S; j++){
        int r = wv + j;
        float p = pb[wv*128 + j];
        o += p * b2f(Vs[r*64 + ((coff ^ (r & 7))*8) + dlo]);
    }
    x[((size_t)(b*TSEQ) + t) * EDIM + h*HDIM + d] += o;
}

// ---------------------------------------------------------------------------
// P-axis attention: q/k already rotated by saqkv epilogue.
// ---------------------------------------------------------------------------
__global__ __launch_bounds__(256) void sa_attn(
    const __hip_bfloat16* __restrict__ qkv2, __hip_bfloat16* __restrict__ o)
{
    const int t = blockIdx.x, h = blockIdx.y, b = blockIdx.z;
    const int p = threadIdx.x >> 6, lane = threadIdx.x & 63;
    const int row0 = (b*TSEQ + t) * PDIM;
    const short* base = (const short*)qkv2 + (size_t)row0 * (3*EDIM);
    const int d = lane;
    float q = b2f(base[(size_t)p*(3*EDIM) + h*HDIM + d]);
    float sc[4];
    #pragma unroll
    for(int j = 0; j < 4; j++){
        float kj = b2f(base[(size_t)j*(3*EDIM) + EDIM + h*HDIM + d]);
        float v = q * kj;
        #pragma unroll
        for(int off = 32; off > 0; off >>= 1) v += __shfl_xor(v, off, 64);
        sc[j] = v * 0.125f;
    }
    float m = fmaxf(fmaxf(sc[0], sc[1]), fmaxf(sc[2], sc[3]));
    float e0 = expf(sc[0]-m), e1 = expf(sc[1]-m), e2 = expf(sc[2]-m), e3 = expf(sc[3]-m);
    float idn = 1.f / (e0 + e1 + e2 + e3);
    float ov = (e0 * b2f(base[0*(3*EDIM) + 2*EDIM + h*HDIM + d])
              + e1 * b2f(base[1*(3*EDIM) + 2*EDIM + h*HDIM + d])
              + e2 * b2f(base[2*(3*EDIM) + 2*EDIM + h*HDIM + d])
              + e3 * b2f(base[3*(3*EDIM) + 2*EDIM + h*HDIM + d])) * idn;
    o[(size_t)(row0 + p) * EDIM + h*HDIM + d] = __float2bfloat16(ov);
}

// ---------------------------------------------------------------------------
extern "C" void kernel_launch(void* const* d_in, const int* in_sizes, int n_in,
                              void* d_out, int out_size, void* d_ws, size_t ws_size,
                              hipStream_t stream)
{
    const int*   tokens    = (const int*)  d_in[0];
    const float* emb       = (const float*)d_in[1];
    const float* bl0g      = (const float*)d_in[2];
    const float* bl0b      = (const float*)d_in[3];
    const float* bl1g      = (const float*)d_in[4];
    const float* bl1b      = (const float*)d_in[5];
    const float* qkv_w     = (const float*)d_in[6];
    const float* ff_w1     = (const float*)d_in[7];
    const float* ff_b1     = (const float*)d_in[8];
    const float* ff_w2     = (const float*)d_in[9];
    const float* ff_b2     = (const float*)d_in[10];
    const float* fin_g     = (const float*)d_in[11];
    const float* fin_b     = (const float*)d_in[12];
    const float* head_w    = (const float*)d_in[13];
    const float* head_b    = (const float*)d_in[14];
    const float* sa_ln0_g  = (const float*)d_in[15];
    const float* sa_ln0_b  = (const float*)d_in[16];
    const float* sa_ln1_g  = (const float*)d_in[17];
    const float* sa_ln1_b  = (const float*)d_in[18];
    const float* sa_qkv_w  = (const float*)d_in[19];
    const float* sa_proj_w = (const float*)d_in[20];
    const float* sa_proj_b = (const float*)d_in[21];
    const float* sa_ff_w1  = (const float*)d_in[22];
    const float* sa_ff_b1  = (const float*)d_in[23];
    const float* sa_ff_w2  = (const float*)d_in[24];
    const float* sa_ff_b2  = (const float*)d_in[25];
    float* out = (float*)d_out;

    // ---- workspace carve-up (~94 MB; harness provides 256 MiB) ----
    char* p = (char*)d_ws;
    auto alloc = [&](size_t bytes){ char* q = p; p += (bytes + 255) & ~(size_t)255; return q; };

    float* logits = (float*)alloc((size_t)NROW2*VDIM*4);        // 4 MB
    float* ropec  = (float*)alloc(512*32*4);
    float* ropes  = (float*)alloc(512*32*4);
    __hip_bfloat16* wqkvT[4]; for(int i=0;i<4;i++) wqkvT[i] = (__hip_bfloat16*)alloc((size_t)768*2304*2);
    __hip_bfloat16* wff1T[4]; for(int i=0;i<4;i++) wff1T[i] = (__hip_bfloat16*)alloc((size_t)768*3072*2);
    __hip_bfloat16* wff2T[4]; for(int i=0;i<4;i++) wff2T[i] = (__hip_bfloat16*)alloc((size_t)3072*768*2);
    __hip_bfloat16* wheadT   = (__hip_bfloat16*)alloc((size_t)768*1024*2);
    __hip_bfloat16* wsaqkvT  = (__hip_bfloat16*)alloc((size_t)256*2304*2);
    __hip_bfloat16* wsaprojT = (__hip_bfloat16*)alloc((size_t)768*256*2);
    __hip_bfloat16* wsaff1T  = (__hip_bfloat16*)alloc((size_t)256*1024*2);
    __hip_bfloat16* wsaff2T  = (__hip_bfloat16*)alloc((size_t)1024*256*2);
    char* U = p;
    // phase 1
    float* x0           = (float*)(U);                           // 3,145,728
    float* x            = (float*)(U + 3145728);                 // 3,145,728
    __hip_bfloat16* h   = (__hip_bfloat16*)(U + 6291456);        // 1,572,864
    __hip_bfloat16* ff1 = (__hip_bfloat16*)(U + 7864320);        // 6,291,456
    __hip_bfloat16* qrb = (__hip_bfloat16*)(U + 14155776);       // 1,572,864
    __hip_bfloat16* krb = (__hip_bfloat16*)(U + 15728640);       // 1,572,864
    __hip_bfloat16* vvb = (__hip_bfloat16*)(U + 17301504);       // 1,572,864
    // phase 2 (aliases phase 1 — dead after head GEMM)
    __hip_bfloat16* h2    = (__hip_bfloat16*)(U);                // 2,097,152
    __hip_bfloat16* qkv2  = (__hip_bfloat16*)(U + 2097152);      // 18,874,368
    __hip_bfloat16* sa_o  = (__hip_bfloat16*)(U + 20971520);     // 6,291,456
    __hip_bfloat16* sa_f1 = (__hip_bfloat16*)(U + 27262976);     // 8,388,608

    // ---- prologue: embed + rope + all 17 weight converts in ONE dispatch ----
    embed_kernel<<<NROW, 192, 0, stream>>>(tokens, emb, x0, x);
    rope_kernel<<<64, 256, 0, stream>>>(ropec, ropes);
    {
        WDs wds; int tot = 0, n = 0;
        auto add = [&](const float* in, __hip_bfloat16* o2, int K, int N){
            wds.d[n++] = WD2{in, o2, K, N, (N/64)*(K/64)};
            tot += (N/64)*(K/64);
        };
        for(int i=0;i<4;i++){
            add(qkv_w + (size_t)i*768*2304, wqkvT[i], 768, 2304);
            add(ff_w1 + (size_t)i*768*3072, wff1T[i], 768, 3072);
            add(ff_w2 + (size_t)i*3072*768, wff2T[i], 3072, 768);
        }
        add(head_w,    wheadT,   768, 1024);
        add(sa_qkv_w,  wsaqkvT,  256, 2304);
        add(sa_proj_w, wsaprojT, 768, 256);
        add(sa_ff_w1,  wsaff1T,  256, 1024);
        add(sa_ff_w2,  wsaff2T, 1024, 256);
        wconv_all<<<tot, 256, 0, stream>>>(wds);
    }

    // ---- 4 main layers ----
    for(int i = 0; i < 4; i++){
        ln_kernel<<<NROW, 256, 0, stream>>>(x, nullptr, bl0g + i*EDIM, bl0b + i*EDIM, h, EDIM);
        gemm64x128<2><<<dim3(18, 16), 256, 0, stream>>>(
            (const short*)h, (const short*)wqkvT[i], nullptr, nullptr,
            qrb, krb, vvb, ropec, ropes, NROW, 3*EDIM, EDIM);
        dim3 agrid(TSEQ/4, NHEAD, BB);
        if(i == 0)      patch_attn2<16><<<agrid, 256, 0, stream>>>(qrb, krb, vvb, x);
        else if(i == 1) patch_attn2<32><<<agrid, 256, 0, stream>>>(qrb, krb, vvb, x);
        else if(i == 2) patch_attn2<64><<<agrid, 256, 0, stream>>>(qrb, krb, vvb, x);
        else            patch_attn2<128><<<agrid, 256, 0, stream>>>(qrb, krb, vvb, x);
        ln_kernel<<<NROW, 256, 0, stream>>>(x, nullptr, bl1g + i*EDIM, bl1b + i*EDIM, h, EDIM);
        gemm64x128<1><<<dim3(24, 16), 256, 0, stream>>>(
            (const short*)h, (const short*)wff1T[i], ff_b1 + (size_t)i*4*EDIM, ff1,
            nullptr, nullptr, nullptr, nullptr, nullptr, NROW, 4*EDIM, EDIM);
        gemm64t<1,0><<<dim3(12, 16), 256, 0, stream>>>(
            (const short*)ff1, (const short*)wff2T[i], ff_b2 + (size_t)i*EDIM, x, x, nullptr,
            NROW, EDIM, 4*EDIM);
    }

    // ---- final LN(x0 + x) + head ----
    ln_kernel<<<NROW, 256, 0, stream>>>(x, x0, fin_g, fin_b, h, EDIM);
    gemm64t<0,0><<<dim3(16, 16), 256, 0, stream>>>(
        (const short*)h, (const short*)wheadT, head_b, nullptr, logits, nullptr,
        NROW, PDIM*VDIM, EDIM);

    // ---- sa block over (B*T*P, V) ----
    ln_kernel<<<NROW2, 256, 0, stream>>>(logits, nullptr, sa_ln0_g, sa_ln0_b, h2, VDIM);
    gemm128<0,0,1,1><<<dim3(18, 32), 256, 0, stream>>>(
        (const short*)h2, (const short*)wsaqkvT, nullptr, nullptr, qkv2,
        ropec, ropes, NROW2, 3*EDIM, VDIM);
    sa_attn<<<dim3(TSEQ, NHEAD, BB), 256, 0, stream>>>(qkv2, sa_o);
    gemm64t<1,0><<<dim3(4, 64), 256, 0, stream>>>(
        (const short*)sa_o, (const short*)wsaprojT, sa_proj_b, logits, logits, nullptr,
        NROW2, VDIM, EDIM);
    ln_kernel<<<NROW2, 256, 0, stream>>>(logits, nullptr, sa_ln1_g, sa_ln1_b, h2, VDIM);
    gemm128<1,0,1,0><<<dim3(8, 32), 256, 0, stream>>>(
        (const short*)h2, (const short*)wsaff1T, sa_ff_b1, nullptr, sa_f1,
        nullptr, nullptr, NROW2, 4*VDIM, VDIM);
    gemm64t<1,1><<<dim3(4, 64), 256, 0, stream>>>(
        (const short*)sa_f1, (const short*)wsaff2T, sa_ff_b2, logits, logits, out,
        NROW2, VDIM, 4*VDIM);
}

// Round 8
// 698.975 us; speedup vs baseline: 1.3755x; 1.0073x over previous
//
#include <hip/hip_runtime.h>
#include <hip/hip_bf16.h>
#include <cstdint>
#include <cstddef>

#define BB    2
#define TSEQ  512
#define EDIM  768
#define NHEAD 12
#define HDIM  64
#define VDIM  256
#define PDIM  4
#define NROW  (BB*TSEQ)        // 1024
#define NROW2 (BB*TSEQ*PDIM)   // 4096

typedef __attribute__((ext_vector_type(8))) short short8;
typedef __attribute__((ext_vector_type(4))) float floatx4;

// one barrier per K-iter: wait only current slab's loads, then barrier.
#define PIPE_BARRIER asm volatile("s_waitcnt vmcnt(0)\n\ts_barrier" ::: "memory")

__device__ __forceinline__ float gelu_f(float v){
    return 0.5f * v * (1.0f + erff(v * 0.70710678118654752f));
}
__device__ __forceinline__ float b2f(short s){
    unsigned u = ((unsigned)(unsigned short)s) << 16;
    float f; __builtin_memcpy(&f, &u, 4); return f;
}
__device__ __forceinline__ short f2bs(float v){
    __hip_bfloat16 h = __float2bfloat16(v);
    short s; __builtin_memcpy(&s, &h, 2); return s;
}
__device__ __forceinline__ void gload16(const void* g, void* l){
    __builtin_amdgcn_global_load_lds((const __attribute__((address_space(1))) void*)g,
                                     (__attribute__((address_space(3))) void*)l, 16, 0, 0);
}

// ---------------------------------------------------------------------------
// All 17 weight conversions in one dispatch. fp32 [K,N] -> bf16 [N,K].
// 64x64 tiles; 16B/lane stores; LDS reads at 2-way aliasing (free).
// ---------------------------------------------------------------------------
struct WD2 { const float* in; __hip_bfloat16* out; int K; int N; int nt; };
struct WDs { WD2 d[17]; };

__global__ __launch_bounds__(256) void wconv_all(WDs a)
{
    int id = blockIdx.x;
    int i = 0;
    while(i < 16 && id >= a.d[i].nt){ id -= a.d[i].nt; i++; }
    WD2 w = a.d[i];
    const int tx = w.N / 64;
    const int n0 = (id % tx) * 64, k0 = (id / tx) * 64;
    __shared__ float t[64][65];
    {
        const int cg = (threadIdx.x & 15) * 4;
        const int rr = threadIdx.x >> 4;           // 0..15
        #pragma unroll
        for(int it = 0; it < 4; it++){
            int r = rr + it*16;
            float4 v = *(const float4*)(w.in + (size_t)(k0 + r) * w.N + n0 + cg);
            t[r][cg+0] = v.x; t[r][cg+1] = v.y; t[r][cg+2] = v.z; t[r][cg+3] = v.w;
        }
    }
    __syncthreads();
    {
        const int cg8 = (threadIdx.x & 7) * 8;
        const int nn  = threadIdx.x >> 3;          // 0..31
        #pragma unroll
        for(int pass = 0; pass < 2; pass++){
            int n = nn + pass*32;
            short8 o;
            #pragma unroll
            for(int j = 0; j < 8; j++) o[j] = f2bs(t[cg8 + j][n]);
            *(short8*)((short*)w.out + (size_t)(n0 + n) * w.K + k0 + cg8) = o;
        }
    }
}

// ---------------------------------------------------------------------------
// MFMA GEMM 128x128, double-buffered pipelined K-loop.
// ROPESA=1: epilogue rotates q/k cols (RoPE at position p=row%4) before store.
// ---------------------------------------------------------------------------
template<int ACT, int RESID, int OUTBF16, int ROPESA>
__global__ __launch_bounds__(256) void gemm128(
    const short* __restrict__ A, const short* __restrict__ Bt,
    const float* __restrict__ bias, const float* __restrict__ resid,
    void* __restrict__ Cout, const float* __restrict__ rc, const float* __restrict__ rs,
    int M, int N, int K)
{
    alignas(16) __shared__ short As[2*128*32];
    alignas(16) __shared__ short Bs[2*128*32];
    const int tid  = threadIdx.x;
    const int lane = tid & 63;
    const int wave = tid >> 6;
    const int bm = blockIdx.y * 128, bn = blockIdx.x * 128;
    const int wm = (wave >> 1) * 64, wn = (wave & 1) * 64;
    const int quad = lane >> 4, l16 = lane & 15;

    floatx4 acc[4][4];
    #pragma unroll
    for(int i = 0; i < 4; i++)
        #pragma unroll
        for(int j = 0; j < 4; j++)
            acc[i][j] = floatx4{0.f, 0.f, 0.f, 0.f};

    const int r  = tid >> 2;
    const int c8 = (tid & 3) * 8;
    const int ldsoff = (tid & 192) * 16;

    auto issue = [&](int k0, int cur){
        char* ab = (char*)As + cur*8192 + ldsoff;
        char* bb = (char*)Bs + cur*8192 + ldsoff;
        gload16(A  + (size_t)(bm + r     ) * K + k0 + c8, ab);
        gload16(A  + (size_t)(bm + r + 64) * K + k0 + c8, ab + 4096);
        gload16(Bt + (size_t)(bn + r     ) * K + k0 + c8, bb);
        gload16(Bt + (size_t)(bn + r + 64) * K + k0 + c8, bb + 4096);
    };

    const int niter = K >> 5;
    issue(0, 0);
    for(int it = 0; it < niter; it++){
        PIPE_BARRIER;
        if(it + 1 < niter) issue((it + 1) << 5, (it + 1) & 1);
        const short* Ab = As + (it & 1) * 4096;
        const short* Bb = Bs + (it & 1) * 4096;
        short8 af[4], bfr[4];
        #pragma unroll
        for(int i = 0; i < 4; i++){
            af[i]  = *(const short8*)&Ab[(wm + i*16 + l16)*32 + quad*8];
            bfr[i] = *(const short8*)&Bb[(wn + i*16 + l16)*32 + quad*8];
        }
        #pragma unroll
        for(int i = 0; i < 4; i++)
            #pragma unroll
            for(int j = 0; j < 4; j++)
                acc[i][j] = __builtin_amdgcn_mfma_f32_16x16x32_bf16(af[i], bfr[j], acc[i][j], 0, 0, 0);
    }

    float* Cf = (float*)Cout;
    __hip_bfloat16* Cb = (__hip_bfloat16*)Cout;

    if(ROPESA){
        const int hb = bn + wn;
        const int region = hb / 768;
        #pragma unroll
        for(int i = 0; i < 4; i++){
            #pragma unroll
            for(int rr = 0; rr < 4; rr++){
                int row = bm + wm + i*16 + quad*4 + rr;
                float a0 = acc[i][0][rr], a1 = acc[i][1][rr];
                float a2 = acc[i][2][rr], a3 = acc[i][3][rr];
                size_t rowb = (size_t)row * N + hb;
                if(region == 2){
                    Cb[rowb + l16]      = __float2bfloat16(a0);
                    Cb[rowb + 16 + l16] = __float2bfloat16(a1);
                    Cb[rowb + 32 + l16] = __float2bfloat16(a2);
                    Cb[rowb + 48 + l16] = __float2bfloat16(a3);
                }else{
                    int p = row & 3;
                    float c0 = rc[p*32 + l16],      s0 = rs[p*32 + l16];
                    float c1 = rc[p*32 + 16 + l16], s1 = rs[p*32 + 16 + l16];
                    Cb[rowb + l16]      = __float2bfloat16(a0*c0 - a2*s0);
                    Cb[rowb + 16 + l16] = __float2bfloat16(a1*c1 - a3*s1);
                    Cb[rowb + 32 + l16] = __float2bfloat16(a0*s0 + a2*c0);
                    Cb[rowb + 48 + l16] = __float2bfloat16(a1*s1 + a3*c1);
                }
            }
        }
        return;
    }

    #pragma unroll
    for(int i = 0; i < 4; i++){
        int row0 = bm + wm + i*16 + quad*4;
        #pragma unroll
        for(int j = 0; j < 4; j++){
            int col = bn + wn + j*16 + l16;
            float bv = bias ? bias[col] : 0.f;
            #pragma unroll
            for(int rr = 0; rr < 4; rr++){
                float v = acc[i][j][rr] + bv;
                if(ACT) v = gelu_f(v);
                if(RESID) v += resid[(size_t)(row0 + rr) * N + col];
                if(OUTBF16) Cb[(size_t)(row0 + rr) * N + col] = __float2bfloat16(v);
                else        Cf[(size_t)(row0 + rr) * N + col] = v;
            }
        }
    }
}

// ---------------------------------------------------------------------------
// MFMA GEMM 64x128, double-buffered. EPI: 1 = bias+gelu bf16 store,
// 2 = phase-1 qkv: RoPE-rotate q/k and write head-major qrb/krb/vvb.
// ---------------------------------------------------------------------------
template<int EPI>
__global__ __launch_bounds__(256) void gemm64x128(
    const short* __restrict__ A, const short* __restrict__ Bt,
    const float* __restrict__ bias, __hip_bfloat16* __restrict__ Cout,
    __hip_bfloat16* __restrict__ qrb, __hip_bfloat16* __restrict__ krb,
    __hip_bfloat16* __restrict__ vvb,
    const float* __restrict__ rc, const float* __restrict__ rs,
    int M, int N, int K)
{
    alignas(16) __shared__ short As[2*64*32];
    alignas(16) __shared__ short Bs[2*128*32];
    const int tid  = threadIdx.x;
    const int lane = tid & 63;
    const int wave = tid >> 6;
    const int bm = blockIdx.y * 64, bn = blockIdx.x * 128;
    const int wm = (wave >> 1) * 32, wn = (wave & 1) * 64;
    const int quad = lane >> 4, l16 = lane & 15;

    floatx4 acc[2][4];
    #pragma unroll
    for(int i = 0; i < 2; i++)
        #pragma unroll
        for(int j = 0; j < 4; j++)
            acc[i][j] = floatx4{0.f, 0.f, 0.f, 0.f};

    const int r  = tid >> 2;
    const int c8 = (tid & 3) * 8;
    const int ldsoff = (tid & 192) * 16;

    auto issue = [&](int k0, int cur){
        char* ab = (char*)As + cur*4096 + ldsoff;
        char* bb = (char*)Bs + cur*8192 + ldsoff;
        gload16(A  + (size_t)(bm + r     ) * K + k0 + c8, ab);
        gload16(Bt + (size_t)(bn + r     ) * K + k0 + c8, bb);
        gload16(Bt + (size_t)(bn + r + 64) * K + k0 + c8, bb + 4096);
    };

    const int niter = K >> 5;
    issue(0, 0);
    for(int it = 0; it < niter; it++){
        PIPE_BARRIER;
        if(it + 1 < niter) issue((it + 1) << 5, (it + 1) & 1);
        const short* Ab = As + (it & 1) * 2048;
        const short* Bb = Bs + (it & 1) * 4096;
        short8 af[2], bfr[4];
        #pragma unroll
        for(int i = 0; i < 2; i++)
            af[i]  = *(const short8*)&Ab[(wm + i*16 + l16)*32 + quad*8];
        #pragma unroll
        for(int j = 0; j < 4; j++)
            bfr[j] = *(const short8*)&Bb[(wn + j*16 + l16)*32 + quad*8];
        #pragma unroll
        for(int i = 0; i < 2; i++)
            #pragma unroll
            for(int j = 0; j < 4; j++)
                acc[i][j] = __builtin_amdgcn_mfma_f32_16x16x32_bf16(af[i], bfr[j], acc[i][j], 0, 0, 0);
    }

    if(EPI == 2){
        const int hb = bn + wn;            // col base of this wave's 64 cols
        const int region = hb / 768;       // 0=q, 1=k, 2=v
        const int h = (hb % 768) >> 6;
        #pragma unroll
        for(int i = 0; i < 2; i++){
            #pragma unroll
            for(int rr = 0; rr < 4; rr++){
                int row = bm + wm + i*16 + quad*4 + rr;
                int t = row & (TSEQ-1), b = row >> 9;
                float a0 = acc[i][0][rr], a1 = acc[i][1][rr];
                float a2 = acc[i][2][rr], a3 = acc[i][3][rr];
                size_t dbase = ((size_t)(b*NHEAD + h)*TSEQ + t)*HDIM;
                if(region == 2){
                    vvb[dbase + l16]      = __float2bfloat16(a0);
                    vvb[dbase + 16 + l16] = __float2bfloat16(a1);
                    vvb[dbase + 32 + l16] = __float2bfloat16(a2);
                    vvb[dbase + 48 + l16] = __float2bfloat16(a3);
                }else{
                    float c0 = rc[t*32 + l16],      s0 = rs[t*32 + l16];
                    float c1 = rc[t*32 + 16 + l16], s1 = rs[t*32 + 16 + l16];
                    __hip_bfloat16* dst = (region == 0) ? qrb : krb;
                    dst[dbase + l16]      = __float2bfloat16(a0*c0 - a2*s0);
                    dst[dbase + 16 + l16] = __float2bfloat16(a1*c1 - a3*s1);
                    dst[dbase + 32 + l16] = __float2bfloat16(a0*s0 + a2*c0);
                    dst[dbase + 48 + l16] = __float2bfloat16(a1*s1 + a3*c1);
                }
            }
        }
        return;
    }

    #pragma unroll
    for(int i = 0; i < 2; i++){
        int row0 = bm + wm + i*16 + quad*4;
        #pragma unroll
        for(int j = 0; j < 4; j++){
            int col = bn + wn + j*16 + l16;
            float bv = bias ? bias[col] : 0.f;
            #pragma unroll
            for(int rr = 0; rr < 4; rr++){
                float v = acc[i][j][rr] + bv;
                if(EPI == 1) v = gelu_f(v);
                Cout[(size_t)(row0 + rr) * N + col] = __float2bfloat16(v);
            }
        }
    }
}

// ---------------------------------------------------------------------------
// 64x64-tile GEMM (bf16 A), double-buffered; fp32 out, optional resid add and
// fused p==0 slice copy to out (OUTC).
// ---------------------------------------------------------------------------
template<int RESID, int OUTC>
__global__ __launch_bounds__(256) void gemm64t(
    const short* __restrict__ A, const short* __restrict__ Bt,
    const float* __restrict__ bias, const float* __restrict__ resid,
    float* __restrict__ Cf, float* __restrict__ outp, int M, int N, int K)
{
    alignas(16) __shared__ short As[2*64*32];
    alignas(16) __shared__ short Bs[2*64*32];
    const int tid  = threadIdx.x;
    const int lane = tid & 63;
    const int wave = tid >> 6;
    const int bm = blockIdx.y * 64, bn = blockIdx.x * 64;
    const int wm = (wave >> 1) * 32, wn = (wave & 1) * 32;
    const int quad = lane >> 4, l16 = lane & 15;

    floatx4 acc[2][2];
    #pragma unroll
    for(int i = 0; i < 2; i++)
        #pragma unroll
        for(int j = 0; j < 2; j++)
            acc[i][j] = floatx4{0.f, 0.f, 0.f, 0.f};

    const int r  = tid >> 2;
    const int c8 = (tid & 3) * 8;
    const int ldsoff = (tid & 192) * 16;

    auto issue = [&](int k0, int cur){
        char* ab = (char*)As + cur*4096 + ldsoff;
        char* bb = (char*)Bs + cur*4096 + ldsoff;
        gload16(A  + (size_t)(bm + r) * K + k0 + c8, ab);
        gload16(Bt + (size_t)(bn + r) * K + k0 + c8, bb);
    };

    const int niter = K >> 5;
    issue(0, 0);
    for(int it = 0; it < niter; it++){
        PIPE_BARRIER;
        if(it + 1 < niter) issue((it + 1) << 5, (it + 1) & 1);
        const short* Ab = As + (it & 1) * 2048;
        const short* Bb = Bs + (it & 1) * 2048;
        short8 af[2], bfr[2];
        #pragma unroll
        for(int i = 0; i < 2; i++){
            af[i]  = *(const short8*)&Ab[(wm + i*16 + l16)*32 + quad*8];
            bfr[i] = *(const short8*)&Bb[(wn + i*16 + l16)*32 + quad*8];
        }
        #pragma unroll
        for(int i = 0; i < 2; i++)
            #pragma unroll
            for(int j = 0; j < 2; j++)
                acc[i][j] = __builtin_amdgcn_mfma_f32_16x16x32_bf16(af[i], bfr[j], acc[i][j], 0, 0, 0);
    }

    #pragma unroll
    for(int i = 0; i < 2; i++){
        int row0 = bm + wm + i*16 + quad*4;
        #pragma unroll
        for(int j = 0; j < 2; j++){
            int col = bn + wn + j*16 + l16;
            float bv = bias ? bias[col] : 0.f;
            #pragma unroll
            for(int rr = 0; rr < 4; rr++){
                int row = row0 + rr;
                float v = acc[i][j][rr] + bv;
                if(RESID) v += resid[(size_t)row * N + col];
                Cf[(size_t)row * N + col] = v;
                if(OUTC && (row & 3) == 0)
                    outp[(size_t)(row >> 2) * N + col] = v;
            }
        }
    }
}

// ---------------------------------------------------------------------------
// LayerNorm over last dim D. fp32 in (optionally +in2), bf16 out.
// ---------------------------------------------------------------------------
__global__ __launch_bounds__(256) void ln_kernel(
    const float* __restrict__ in, const float* __restrict__ in2,
    const float* __restrict__ g, const float* __restrict__ bta,
    __hip_bfloat16* __restrict__ out, int D)
{
    const int row = blockIdx.x;
    const float* xr  = in + (size_t)row * D;
    const float* x2r = in2 ? in2 + (size_t)row * D : nullptr;
    const int tid = threadIdx.x;
    const int nper = D / 256;
    float vals[3];
    float sum = 0.f, sq = 0.f;
    for(int i = 0; i < nper; i++){
        int d = tid + i*256;
        float v = xr[d];
        if(x2r) v += x2r[d];
        vals[i] = v; sum += v; sq += v*v;
    }
    #pragma unroll
    for(int off = 32; off > 0; off >>= 1){
        sum += __shfl_xor(sum, off, 64);
        sq  += __shfl_xor(sq,  off, 64);
    }
    __shared__ float ssum[4], ssq[4];
    __shared__ float smean, srstd;
    int wid = tid >> 6;
    if((tid & 63) == 0){ ssum[wid] = sum; ssq[wid] = sq; }
    __syncthreads();
    if(tid == 0){
        float S = 0.f, Q = 0.f;
        for(int w = 0; w < 4; w++){ S += ssum[w]; Q += ssq[w]; }
        float m = S / D;
        float var = Q / D - m*m;
        smean = m;
        srstd = rsqrtf(fmaxf(var, 0.f) + 1e-5f);
    }
    __syncthreads();
    float m = smean, rs2 = srstd;
    for(int i = 0; i < nper; i++){
        int d = tid + i*256;
        out[(size_t)row*D + d] = __float2bfloat16((vals[i] - m) * rs2 * g[d] + bta[d]);
    }
}

// ---------------------------------------------------------------------------
__global__ __launch_bounds__(192) void embed_kernel(
    const int* __restrict__ tokens, const float* __restrict__ emb,
    float* __restrict__ x0, float* __restrict__ x)
{
    const int row = blockIdx.x;
    const int tok = tokens[row];
    const float4* src = (const float4*)(emb + (size_t)tok * EDIM);
    float4* d0 = (float4*)(x0 + (size_t)row * EDIM);
    float4* d1 = (float4*)(x  + (size_t)row * EDIM);
    for(int i = threadIdx.x; i < EDIM/4; i += blockDim.x){
        float4 v = src[i]; d0[i] = v; d1[i] = v;
    }
}

// ---------------------------------------------------------------------------
__global__ __launch_bounds__(256) void rope_kernel(float* __restrict__ rc, float* __restrict__ rs)
{
    int i = blockIdx.x * 256 + threadIdx.x;   // 512*32 = 16384
    int pos = i >> 5, d = i & 31;
    float inv = powf(10000.0f, -(float)(2*d) / 64.0f);
    float f = (float)pos * inv;
    rc[i] = cosf(f);
    rs[i] = sinf(f);
}

// ---------------------------------------------------------------------------
// Sliding-window attention. 4 waves/block = 4 consecutive queries.
// ---------------------------------------------------------------------------
template<int S>
__global__ __launch_bounds__(256) void patch_attn2(
    const __hip_bfloat16* __restrict__ qr, const __hip_bfloat16* __restrict__ kr,
    const __hip_bfloat16* __restrict__ vv, float* __restrict__ x)
{
    constexpr int W = S + 3;
    alignas(16) __shared__ short Ks[W*64];
    alignas(16) __shared__ short Vs[W*64];
    __shared__ float qlds[4*64];
    __shared__ float pb[4*128];

    const int t0 = blockIdx.x * 4;
    const int h = blockIdx.y, b = blockIdx.z;
    const int tid = threadIdx.x;
    const int wv = tid >> 6, lane = tid & 63;
    const size_t headbase = ((size_t)(b*NHEAD + h)) * TSEQ;

    const int c = tid & 7;
    for(int r = tid >> 3; r < W; r += 32){
        int g = t0 - S + 1 + r;
        int gc = g < 0 ? 0 : g;
        int sc = (c ^ (r & 7)) * 8;
        *(short8*)&Ks[r*64 + sc] = *(const short8*)((const short*)kr + (headbase + gc)*64 + c*8);
        *(short8*)&Vs[r*64 + sc] = *(const short8*)((const short*)vv + (headbase + gc)*64 + c*8);
    }
    qlds[wv*64 + lane] = __bfloat162float(qr[(headbase + t0 + wv)*64 + lane]);
    __syncthreads();

    const int t = t0 + wv;
    const int r0 = (S >= 64) ? (wv + lane) : ((lane < S) ? (wv + lane) : 0);
    const int r1 = wv + lane + 64;
    float a0 = 0.f, a1 = 0.f;
    #pragma unroll
    for(int ch = 0; ch < 8; ch++){
        float4 qa = *(const float4*)&qlds[wv*64 + ch*8];
        float4 qb = *(const float4*)&qlds[wv*64 + ch*8 + 4];
        short8 k0 = *(const short8*)&Ks[r0*64 + ((ch ^ (r0 & 7))*8)];
        a0 += qa.x*b2f(k0[0]) + qa.y*b2f(k0[1]) + qa.z*b2f(k0[2]) + qa.w*b2f(k0[3])
            + qb.x*b2f(k0[4]) + qb.y*b2f(k0[5]) + qb.z*b2f(k0[6]) + qb.w*b2f(k0[7]);
        if(S == 128){
            short8 k1 = *(const short8*)&Ks[r1*64 + ((ch ^ (r1 & 7))*8)];
            a1 += qa.x*b2f(k1[0]) + qa.y*b2f(k1[1]) + qa.z*b2f(k1[2]) + qa.w*b2f(k1[3])
                + qb.x*b2f(k1[4]) + qb.y*b2f(k1[5]) + qb.z*b2f(k1[6]) + qb.w*b2f(k1[7]);
        }
    }
    const int key0 = t - S + 1 + lane;
    const bool v0 = (lane < S) && (key0 >= 0);
    const bool v1 = (S == 128) && (key0 + 64 >= 0);
    float s0 = v0 ? a0 * 0.125f : -1e30f;
    float s1 = v1 ? a1 * 0.125f : -1e30f;
    float mx = fmaxf(s0, s1);
    #pragma unroll
    for(int off = 32; off > 0; off >>= 1) mx = fmaxf(mx, __shfl_xor(mx, off, 64));
    float p0 = v0 ? expf(s0 - mx) : 0.f;
    float p1 = v1 ? expf(s1 - mx) : 0.f;
    float sm = p0 + p1;
    #pragma unroll
    for(int off = 32; off > 0; off >>= 1) sm += __shfl_xor(sm, off, 64);
    const float inv = 1.f / sm;
    pb[wv*128 + lane] = p0 * inv;
    if(S == 128) pb[wv*128 + lane + 64] = p1 * inv;
    __syncthreads();

    const int d = lane;
    const int coff = d >> 3, dlo = d & 7;
    float o = 0.f;
    #pragma unroll 8
    for(int j = 0; j < S; j++){
        int r = wv + j;
        float p = pb[wv*128 + j];
        o += p * b2f(Vs[r*64 + ((coff ^ (r & 7))*8) + dlo]);
    }
    x[((size_t)(b*TSEQ) + t) * EDIM + h*HDIM + d] += o;
}

// ---------------------------------------------------------------------------
// P-axis attention: q/k already rotated by saqkv epilogue.
// ---------------------------------------------------------------------------
__global__ __launch_bounds__(256) void sa_attn(
    const __hip_bfloat16* __restrict__ qkv2, __hip_bfloat16* __restrict__ o)
{
    const int t = blockIdx.x, h = blockIdx.y, b = blockIdx.z;
    const int p = threadIdx.x >> 6, lane = threadIdx.x & 63;
    const int row0 = (b*TSEQ + t) * PDIM;
    const short* base = (const short*)qkv2 + (size_t)row0 * (3*EDIM);
    const int d = lane;
    float q = b2f(base[(size_t)p*(3*EDIM) + h*HDIM + d]);
    float sc[4];
    #pragma unroll
    for(int j = 0; j < 4; j++){
        float kj = b2f(base[(size_t)j*(3*EDIM) + EDIM + h*HDIM + d]);
        float v = q * kj;
        #pragma unroll
        for(int off = 32; off > 0; off >>= 1) v += __shfl_xor(v, off, 64);
        sc[j] = v * 0.125f;
    }
    float m = fmaxf(fmaxf(sc[0], sc[1]), fmaxf(sc[2], sc[3]));
    float e0 = expf(sc[0]-m), e1 = expf(sc[1]-m), e2 = expf(sc[2]-m), e3 = expf(sc[3]-m);
    float idn = 1.f / (e0 + e1 + e2 + e3);
    float ov = (e0 * b2f(base[0*(3*EDIM) + 2*EDIM + h*HDIM + d])
              + e1 * b2f(base[1*(3*EDIM) + 2*EDIM + h*HDIM + d])
              + e2 * b2f(base[2*(3*EDIM) + 2*EDIM + h*HDIM + d])
              + e3 * b2f(base[3*(3*EDIM) + 2*EDIM + h*HDIM + d])) * idn;
    o[(size_t)(row0 + p) * EDIM + h*HDIM + d] = __float2bfloat16(ov);
}

// ---------------------------------------------------------------------------
extern "C" void kernel_launch(void* const* d_in, const int* in_sizes, int n_in,
                              void* d_out, int out_size, void* d_ws, size_t ws_size,
                              hipStream_t stream)
{
    const int*   tokens    = (const int*)  d_in[0];
    const float* emb       = (const float*)d_in[1];
    const float* bl0g      = (const float*)d_in[2];
    const float* bl0b      = (const float*)d_in[3];
    const float* bl1g      = (const float*)d_in[4];
    const float* bl1b      = (const float*)d_in[5];
    const float* qkv_w     = (const float*)d_in[6];
    const float* ff_w1     = (const float*)d_in[7];
    const float* ff_b1     = (const float*)d_in[8];
    const float* ff_w2     = (const float*)d_in[9];
    const float* ff_b2     = (const float*)d_in[10];
    const float* fin_g     = (const float*)d_in[11];
    const float* fin_b     = (const float*)d_in[12];
    const float* head_w    = (const float*)d_in[13];
    const float* head_b    = (const float*)d_in[14];
    const float* sa_ln0_g  = (const float*)d_in[15];
    const float* sa_ln0_b  = (const float*)d_in[16];
    const float* sa_ln1_g  = (const float*)d_in[17];
    const float* sa_ln1_b  = (const float*)d_in[18];
    const float* sa_qkv_w  = (const float*)d_in[19];
    const float* sa_proj_w = (const float*)d_in[20];
    const float* sa_proj_b = (const float*)d_in[21];
    const float* sa_ff_w1  = (const float*)d_in[22];
    const float* sa_ff_b1  = (const float*)d_in[23];
    const float* sa_ff_w2  = (const float*)d_in[24];
    const float* sa_ff_b2  = (const float*)d_in[25];
    float* out = (float*)d_out;

    // ---- workspace carve-up (~94 MB; harness provides 256 MiB) ----
    char* p = (char*)d_ws;
    auto alloc = [&](size_t bytes){ char* q = p; p += (bytes + 255) & ~(size_t)255; return q; };

    float* logits = (float*)alloc((size_t)NROW2*VDIM*4);        // 4 MB
    float* ropec  = (float*)alloc(512*32*4);
    float* ropes  = (float*)alloc(512*32*4);
    __hip_bfloat16* wqkvT[4]; for(int i=0;i<4;i++) wqkvT[i] = (__hip_bfloat16*)alloc((size_t)768*2304*2);
    __hip_bfloat16* wff1T[4]; for(int i=0;i<4;i++) wff1T[i] = (__hip_bfloat16*)alloc((size_t)768*3072*2);
    __hip_bfloat16* wff2T[4]; for(int i=0;i<4;i++) wff2T[i] = (__hip_bfloat16*)alloc((size_t)3072*768*2);
    __hip_bfloat16* wheadT   = (__hip_bfloat16*)alloc((size_t)768*1024*2);
    __hip_bfloat16* wsaqkvT  = (__hip_bfloat16*)alloc((size_t)256*2304*2);
    __hip_bfloat16* wsaprojT = (__hip_bfloat16*)alloc((size_t)768*256*2);
    __hip_bfloat16* wsaff1T  = (__hip_bfloat16*)alloc((size_t)256*1024*2);
    __hip_bfloat16* wsaff2T  = (__hip_bfloat16*)alloc((size_t)1024*256*2);
    char* U = p;
    // phase 1
    float* x0           = (float*)(U);                           // 3,145,728
    float* x            = (float*)(U + 3145728);                 // 3,145,728
    __hip_bfloat16* h   = (__hip_bfloat16*)(U + 6291456);        // 1,572,864
    __hip_bfloat16* ff1 = (__hip_bfloat16*)(U + 7864320);        // 6,291,456
    __hip_bfloat16* qrb = (__hip_bfloat16*)(U + 14155776);       // 1,572,864
    __hip_bfloat16* krb = (__hip_bfloat16*)(U + 15728640);       // 1,572,864
    __hip_bfloat16* vvb = (__hip_bfloat16*)(U + 17301504);       // 1,572,864
    // phase 2 (aliases phase 1 — dead after head GEMM)
    __hip_bfloat16* h2    = (__hip_bfloat16*)(U);                // 2,097,152
    __hip_bfloat16* qkv2  = (__hip_bfloat16*)(U + 2097152);      // 18,874,368
    __hip_bfloat16* sa_o  = (__hip_bfloat16*)(U + 20971520);     // 6,291,456
    __hip_bfloat16* sa_f1 = (__hip_bfloat16*)(U + 27262976);     // 8,388,608

    // ---- prologue: embed + rope + all 17 weight converts in ONE dispatch ----
    embed_kernel<<<NROW, 192, 0, stream>>>(tokens, emb, x0, x);
    rope_kernel<<<64, 256, 0, stream>>>(ropec, ropes);
    {
        WDs wds; int tot = 0, n = 0;
        auto add = [&](const float* in, __hip_bfloat16* o2, int K, int N){
            wds.d[n++] = WD2{in, o2, K, N, (N/64)*(K/64)};
            tot += (N/64)*(K/64);
        };
        for(int i=0;i<4;i++){
            add(qkv_w + (size_t)i*768*2304, wqkvT[i], 768, 2304);
            add(ff_w1 + (size_t)i*768*3072, wff1T[i], 768, 3072);
            add(ff_w2 + (size_t)i*3072*768, wff2T[i], 3072, 768);
        }
        add(head_w,    wheadT,   768, 1024);
        add(sa_qkv_w,  wsaqkvT,  256, 2304);
        add(sa_proj_w, wsaprojT, 768, 256);
        add(sa_ff_w1,  wsaff1T,  256, 1024);
        add(sa_ff_w2,  wsaff2T, 1024, 256);
        wconv_all<<<tot, 256, 0, stream>>>(wds);
    }

    // ---- 4 main layers ----
    for(int i = 0; i < 4; i++){
        ln_kernel<<<NROW, 256, 0, stream>>>(x, nullptr, bl0g + i*EDIM, bl0b + i*EDIM, h, EDIM);
        gemm64x128<2><<<dim3(18, 16), 256, 0, stream>>>(
            (const short*)h, (const short*)wqkvT[i], nullptr, nullptr,
            qrb, krb, vvb, ropec, ropes, NROW, 3*EDIM, EDIM);
        dim3 agrid(TSEQ/4, NHEAD, BB);
        if(i == 0)      patch_attn2<16><<<agrid, 256, 0, stream>>>(qrb, krb, vvb, x);
        else if(i == 1) patch_attn2<32><<<agrid, 256, 0, stream>>>(qrb, krb, vvb, x);
        else if(i == 2) patch_attn2<64><<<agrid, 256, 0, stream>>>(qrb, krb, vvb, x);
        else            patch_attn2<128><<<agrid, 256, 0, stream>>>(qrb, krb, vvb, x);
        ln_kernel<<<NROW, 256, 0, stream>>>(x, nullptr, bl1g + i*EDIM, bl1b + i*EDIM, h, EDIM);
        gemm64x128<1><<<dim3(24, 16), 256, 0, stream>>>(
            (const short*)h, (const short*)wff1T[i], ff_b1 + (size_t)i*4*EDIM, ff1,
            nullptr, nullptr, nullptr, nullptr, nullptr, NROW, 4*EDIM, EDIM);
        gemm64t<1,0><<<dim3(12, 16), 256, 0, stream>>>(
            (const short*)ff1, (const short*)wff2T[i], ff_b2 + (size_t)i*EDIM, x, x, nullptr,
            NROW, EDIM, 4*EDIM);
    }

    // ---- final LN(x0 + x) + head ----
    ln_kernel<<<NROW, 256, 0, stream>>>(x, x0, fin_g, fin_b, h, EDIM);
    gemm64t<0,0><<<dim3(16, 16), 256, 0, stream>>>(
        (const short*)h, (const short*)wheadT, head_b, nullptr, logits, nullptr,
        NROW, PDIM*VDIM, EDIM);

    // ---- sa block over (B*T*P, V) ----
    ln_kernel<<<NROW2, 256, 0, stream>>>(logits, nullptr, sa_ln0_g, sa_ln0_b, h2, VDIM);
    gemm128<0,0,1,1><<<dim3(18, 32), 256, 0, stream>>>(
        (const short*)h2, (const short*)wsaqkvT, nullptr, nullptr, qkv2,
        ropec, ropes, NROW2, 3*EDIM, VDIM);
    sa_attn<<<dim3(TSEQ, NHEAD, BB), 256, 0, stream>>>(qkv2, sa_o);
    gemm64t<1,0><<<dim3(4, 64), 256, 0, stream>>>(
        (const short*)sa_o, (const short*)wsaprojT, sa_proj_b, logits, logits, nullptr,
        NROW2, VDIM, EDIM);
    ln_kernel<<<NROW2, 256, 0, stream>>>(logits, nullptr, sa_ln1_g, sa_ln1_b, h2, VDIM);
    gemm128<1,0,1,0><<<dim3(8, 32), 256, 0, stream>>>(
        (const short*)h2, (const short*)wsaff1T, sa_ff_b1, nullptr, sa_f1,
        nullptr, nullptr, NROW2, 4*VDIM, VDIM);
    gemm64t<1,1><<<dim3(4, 64), 256, 0, stream>>>(
        (const short*)sa_f1, (const short*)wsaff2T, sa_ff_b2, logits, logits, out,
        NROW2, VDIM, 4*VDIM);
}